// Round 13
// baseline (725.847 us; speedup 1.0000x reference)
//
#include <hip/hip_runtime.h>

#define LN_EPS 1e-5f

typedef unsigned short u16;
typedef u16 u16x8 __attribute__((ext_vector_type(8)));
typedef __bf16 bf16x8 __attribute__((ext_vector_type(8)));
typedef float f32x4 __attribute__((ext_vector_type(4)));
typedef float f32x2 __attribute__((ext_vector_type(2)));

__device__ __forceinline__ u16 f2bf(float f){
  return __builtin_bit_cast(u16, (__bf16)f);
}
__device__ __forceinline__ float bf2f(u16 b){
  return (float)__builtin_bit_cast(__bf16, b);
}
__device__ __forceinline__ f32x4 mfma16(u16x8 a, u16x8 b, f32x4 c){
  return __builtin_amdgcn_mfma_f32_16x16x32_bf16(
      __builtin_bit_cast(bf16x8, a), __builtin_bit_cast(bf16x8, b), c, 0, 0, 0);
}
// LDS h-tile: [64 rows][512 k] bf16, XOR swizzle on k (8-elem granules)
__device__ __forceinline__ int uidx(int row, int k){
  return row * 512 + (k ^ ((row & 7) << 3));
}

__device__ __forceinline__ void zero_acc(f32x4 (&acc)[4][4]){
  #pragma unroll
  for (int mt = 0; mt < 4; ++mt)
    #pragma unroll
    for (int ct = 0; ct < 4; ++ct){
      f32x4 z = {0.f, 0.f, 0.f, 0.f};
      acc[mt][ct] = z;
    }
}

// Issue first kt's 4 B-fragment loads BEFORE the preceding barrier (in flight
// across s_barrier; hides cold-start L2 latency).
__device__ __forceinline__ void preload_b4(const u16* __restrict__ Bp, int wave, int lane,
                                           u16x8 (&b)[4]){
  const u16* bb = Bp + ((size_t)(wave * 4) * 64 + lane) * 8;
  #pragma unroll
  for (int ct = 0; ct < 4; ++ct) b[ct] = *(const u16x8*)&bb[ct * 512];
}

// GEMM, A from LDS (64 rows), B from global (N=512 packing, kt-stride 16384),
// 1-deep register prefetch (~88 VGPR). b_cur arrives preloaded.
__device__ __forceinline__ void gemm_pipe(const u16* hA, const u16* __restrict__ Bp,
                                          f32x4 (&acc)[4][4], int wave, int lane,
                                          u16x8 (&b_cur)[4]){
  int lrow = lane & 15, lhi = lane >> 4;
  const u16* bb = Bp + ((size_t)(wave * 4) * 64 + lane) * 8;
  u16x8 b_nxt[4], a[4];
  #pragma unroll
  for (int kt = 0; kt < 16; ++kt){
    #pragma unroll
    for (int mt = 0; mt < 4; ++mt)
      a[mt] = *(const u16x8*)&hA[uidx(mt * 16 + lrow, kt * 32 + lhi * 8)];
    if (kt < 15){
      #pragma unroll
      for (int ct = 0; ct < 4; ++ct)
        b_nxt[ct] = *(const u16x8*)&bb[(size_t)(kt + 1) * 16384 + ct * 512];
    }
    __builtin_amdgcn_s_setprio(1);
    #pragma unroll
    for (int ct = 0; ct < 4; ++ct)
      #pragma unroll
      for (int mt = 0; mt < 4; ++mt)
        acc[mt][ct] = mfma16(a[mt], b_cur[ct], acc[mt][ct]);
    __builtin_amdgcn_s_setprio(0);
    #pragma unroll
    for (int ct = 0; ct < 4; ++ct) b_cur[ct] = b_nxt[ct];
  }
}

// K=1024 GEMM, A rows from TWO global sources (nodeb | aggb), B = nw1p (N16=32
// packing, kt-stride 16384, KT=32).
__device__ __forceinline__ void gemm_k1024_gA(const u16* __restrict__ A0,
                                              const u16* __restrict__ A1, size_t row0,
                                              const u16* __restrict__ Bp,
                                              f32x4 (&acc)[4][4], int wave, int lane){
  int lrow = lane & 15, lhi = lane >> 4;
  const u16* bb = Bp + ((size_t)(wave * 4) * 64 + lane) * 8;
  const u16* a0 = A0 + (row0 + lrow) * 512 + lhi * 8;
  const u16* a1 = A1 + (row0 + lrow) * 512 + lhi * 8;
  u16x8 b_cur[4], b_nxt[4], a[4];
  #pragma unroll
  for (int ct = 0; ct < 4; ++ct) b_cur[ct] = *(const u16x8*)&bb[ct * 512];
  #pragma unroll
  for (int kt = 0; kt < 32; ++kt){
    const u16* ab = (kt < 16) ? a0 : a1;
    int kk = (kt & 15) * 32;
    #pragma unroll
    for (int mt = 0; mt < 4; ++mt)
      a[mt] = *(const u16x8*)&ab[mt * 8192 + kk];
    if (kt < 31){
      #pragma unroll
      for (int ct = 0; ct < 4; ++ct)
        b_nxt[ct] = *(const u16x8*)&bb[(size_t)(kt + 1) * 16384 + ct * 512];
    }
    __builtin_amdgcn_s_setprio(1);
    #pragma unroll
    for (int ct = 0; ct < 4; ++ct)
      #pragma unroll
      for (int mt = 0; mt < 4; ++mt)
        acc[mt][ct] = mfma16(a[mt], b_cur[ct], acc[mt][ct]);
    __builtin_amdgcn_s_setprio(0);
    #pragma unroll
    for (int ct = 0; ct < 4; ++ct) b_cur[ct] = b_nxt[ct];
  }
}

// GEMM over hA with custom B base/kt-stride (for N=1024 w1p packing).
__device__ __forceinline__ void gemm_pipe_s(const u16* hA, const u16* __restrict__ bbBase,
                                            int ktStride, f32x4 (&acc)[4][4],
                                            int lane){
  int lrow = lane & 15, lhi = lane >> 4;
  u16x8 b_cur[4], b_nxt[4], a[4];
  #pragma unroll
  for (int ct = 0; ct < 4; ++ct) b_cur[ct] = *(const u16x8*)&bbBase[ct * 512];
  #pragma unroll
  for (int kt = 0; kt < 16; ++kt){
    #pragma unroll
    for (int mt = 0; mt < 4; ++mt)
      a[mt] = *(const u16x8*)&hA[uidx(mt * 16 + lrow, kt * 32 + lhi * 8)];
    if (kt < 15){
      #pragma unroll
      for (int ct = 0; ct < 4; ++ct)
        b_nxt[ct] = *(const u16x8*)&bbBase[(size_t)(kt + 1) * ktStride + ct * 512];
    }
    __builtin_amdgcn_s_setprio(1);
    #pragma unroll
    for (int ct = 0; ct < 4; ++ct)
      #pragma unroll
      for (int mt = 0; mt < 4; ++mt)
        acc[mt][ct] = mfma16(a[mt], b_cur[ct], acc[mt][ct]);
    __builtin_amdgcn_s_setprio(0);
    #pragma unroll
    for (int ct = 0; ct < 4; ++ct) b_cur[ct] = b_nxt[ct];
  }
}

__device__ __forceinline__ void add_bias8(f32x4 (&acc)[4][4], const float* __restrict__ b,
                                          int wave, int lane){
  int lrow = lane & 15;
  #pragma unroll
  for (int ct = 0; ct < 4; ++ct){
    float bb = b[wave * 64 + ct * 16 + lrow];
    #pragma unroll
    for (int mt = 0; mt < 4; ++mt)
      #pragma unroll
      for (int r = 0; r < 4; ++r) acc[mt][ct][r] += bb;
  }
}

// acc += bias; relu; write bf16 into hA (swizzled). (r1 stage of node MLP.)
__device__ __forceinline__ void relu_to_lds(f32x4 (&acc)[4][4], u16* hA,
                                            const float* __restrict__ b,
                                            int wave, int lane){
  int lrow = lane & 15, lhi = lane >> 4;
  #pragma unroll
  for (int ct = 0; ct < 4; ++ct){
    int c = wave * 64 + ct * 16 + lrow;
    float bb = b[c];
    #pragma unroll
    for (int mt = 0; mt < 4; ++mt)
      #pragma unroll
      for (int r = 0; r < 4; ++r){
        int row = mt * 16 + lhi * 4 + r;
        hA[uidx(row, c)] = f2bf(fmaxf(acc[mt][ct][r] + bb, 0.f));
      }
  }
}

// acc += b2; LayerNorm over 512 cols per row; relu.
// TO_ACC=0: write bf16 into hA (only rows < rowcap); TO_ACC=1: result into acc.
template<int TO_ACC>
__device__ __forceinline__ void ln_relu8_t(f32x4 (&acc)[4][4], u16* hA,
    f32x2 (*stats)[8], f32x2* mufb,
    const float* __restrict__ b2, const float* __restrict__ g, const float* __restrict__ bt,
    int wave, int lane, int tid, int rowcap)
{
  int lrow = lane & 15, lhi = lane >> 4;
  float s1[4][4], s2[4][4];
  #pragma unroll
  for (int mt = 0; mt < 4; ++mt)
    #pragma unroll
    for (int r = 0; r < 4; ++r){ s1[mt][r] = 0.f; s2[mt][r] = 0.f; }
  #pragma unroll
  for (int ct = 0; ct < 4; ++ct){
    int c = wave * 64 + ct * 16 + lrow;
    float bb = b2[c];
    #pragma unroll
    for (int mt = 0; mt < 4; ++mt)
      #pragma unroll
      for (int r = 0; r < 4; ++r){
        float x = acc[mt][ct][r] + bb;
        acc[mt][ct][r] = x;
        s1[mt][r] += x; s2[mt][r] += x * x;
      }
  }
  #pragma unroll
  for (int off = 1; off < 16; off <<= 1){
    #pragma unroll
    for (int mt = 0; mt < 4; ++mt)
      #pragma unroll
      for (int r = 0; r < 4; ++r){
        s1[mt][r] += __shfl_xor(s1[mt][r], off);
        s2[mt][r] += __shfl_xor(s2[mt][r], off);
      }
  }
  float sa1 = 0.f, sa2 = 0.f;
  #pragma unroll
  for (int mt = 0; mt < 4; ++mt)
    #pragma unroll
    for (int r = 0; r < 4; ++r)
      if (lrow == mt * 4 + r){ sa1 = s1[mt][r]; sa2 = s2[mt][r]; }
  int rowa = (lrow >> 2) * 16 + lhi * 4 + (lrow & 3);
  f32x2 pa = {sa1, sa2};
  stats[rowa][wave] = pa;
  __syncthreads();              // also: all waves done reading hA (prev GEMM)
  if (tid < 64){
    float a = 0.f, b = 0.f;
    #pragma unroll
    for (int w = 0; w < 8; ++w){ a += stats[tid][w][0]; b += stats[tid][w][1]; }
    float mu  = a * (1.f / 512.f);
    float var = b * (1.f / 512.f) - mu * mu;
    f32x2 mr = {mu, rsqrtf(fmaxf(var, 0.f) + LN_EPS)};
    mufb[tid] = mr;
  }
  __syncthreads();
  float gv[4], btv[4];
  #pragma unroll
  for (int ct = 0; ct < 4; ++ct){
    int c = wave * 64 + ct * 16 + lrow;
    gv[ct] = g[c]; btv[ct] = bt[c];
  }
  #pragma unroll
  for (int mt = 0; mt < 4; ++mt)
    #pragma unroll
    for (int r = 0; r < 4; ++r){
      int row = mt * 16 + lhi * 4 + r;
      f32x2 mr = mufb[row];
      #pragma unroll
      for (int ct = 0; ct < 4; ++ct){
        int c = wave * 64 + ct * 16 + lrow;
        float x = (acc[mt][ct][r] - mr[0]) * mr[1] * gv[ct] + btv[ct];
        if (TO_ACC) acc[mt][ct][r] = fmaxf(x, 0.f);
        else if (row < rowcap) hA[uidx(row, c)] = f2bf(fmaxf(x, 0.f));
      }
    }
  // TO_ACC=0 caller: barrier before any cross-thread hA read.
}

// dot each row with weight vector w; per-wave partial -> stats[row][wave].x
__device__ __forceinline__ void head_partial8(f32x4 (&acc)[4][4], const float* __restrict__ w,
                                              f32x2 (*stats)[8], int wave, int lane)
{
  int lrow = lane & 15, lhi = lane >> 4;
  float hs[4][4];
  #pragma unroll
  for (int mt = 0; mt < 4; ++mt)
    #pragma unroll
    for (int r = 0; r < 4; ++r) hs[mt][r] = 0.f;
  #pragma unroll
  for (int ct = 0; ct < 4; ++ct){
    int c = wave * 64 + ct * 16 + lrow;
    float f = w[c];
    #pragma unroll
    for (int mt = 0; mt < 4; ++mt)
      #pragma unroll
      for (int r = 0; r < 4; ++r) hs[mt][r] += acc[mt][ct][r] * f;
  }
  #pragma unroll
  for (int off = 1; off < 16; off <<= 1)
    #pragma unroll
    for (int mt = 0; mt < 4; ++mt)
      #pragma unroll
      for (int r = 0; r < 4; ++r) hs[mt][r] += __shfl_xor(hs[mt][r], off);
  float sa = 0.f;
  #pragma unroll
  for (int mt = 0; mt < 4; ++mt)
    #pragma unroll
    for (int r = 0; r < 4; ++r)
      if (lrow == mt * 4 + r) sa = hs[mt][r];
  int rowa = (lrow >> 2) * 16 + lhi * 4 + (lrow & 3);
  f32x2 pa = {sa, 0.f};
  stats[rowa][wave] = pa;
}

// Staging: h1 = relu(P[i]+Q[j]+b1) for graph gg into hA rows 0..48 (+ zero pad
// rows 49..63 iff PAD). bias[] = per-thread hoisted b1.
template<int PAD>
__device__ __forceinline__ void stage_h1(const u16* __restrict__ PQ, int gg, u16* hA,
                                         const float* bias, int wave, int lane){
  const u16* Pg = PQ + (size_t)gg * 7 * 1024;
  u16x8 pA, qA, pB, qB;
  {
    int e = wave;
    int i = e / 7, j = e % 7;
    pA = *(const u16x8*)&Pg[(size_t)i * 1024 + lane * 8];
    qA = *(const u16x8*)&Pg[(size_t)j * 1024 + 512 + lane * 8];
  }
  #pragma unroll
  for (int it = 0; it < 8; ++it){
    int e = it * 8 + wave;
    if (it < 7){
      int e2 = e + 8;
      if (e2 < 49){
        int i = e2 / 7, j = e2 % 7;
        pB = *(const u16x8*)&Pg[(size_t)i * 1024 + lane * 8];
        qB = *(const u16x8*)&Pg[(size_t)j * 1024 + 512 + lane * 8];
      }
    }
    if (e < 49){
      u16x8 o;
      #pragma unroll
      for (int u = 0; u < 8; ++u)
        o[u] = f2bf(fmaxf(bf2f(pA[u]) + bf2f(qA[u]) + bias[u], 0.f));
      *(u16x8*)&hA[uidx(e, lane * 8)] = o;
    } else if (PAD){
      u16x8 o;
      #pragma unroll
      for (int u = 0; u < 8; ++u) o[u] = 0;
      *(u16x8*)&hA[uidx(e, lane * 8)] = o;
    }
    pA = pB; qA = qB;
  }
}

// column sums: hsum[i][c] = sum_j h2n[7i+j][c] -> rows dstRow..dstRow+6 (bf16)
__device__ __forceinline__ void colsum7(u16* hA, int dstRow, int tid){
  int c = tid;   // 0..511
  #pragma unroll
  for (int i = 0; i < 7; ++i){
    float s = 0.f;
    #pragma unroll
    for (int j = 0; j < 7; ++j)
      s += bf2f(hA[uidx(7 * i + j, c)]);
    hA[uidx(dstRow + i, c)] = f2bf(s);
  }
}

// ============ edge pass 0: TWO graphs per block, shared w3-GEMM2 ============
// agg[i] = hsum[i] @ w3 + 7*b3, with hsum_A in rows 49..55, hsum_B in 56..62.
__global__ __launch_bounds__(512, 2) void edge0_kernel(
    const u16* __restrict__ PQ, const u16* __restrict__ w2p, const u16* __restrict__ w3p,
    const float* __restrict__ b1, const float* __restrict__ b2,
    const float* __restrict__ g, const float* __restrict__ bt, const float* __restrict__ b3,
    u16* __restrict__ agg)
{
  __shared__ alignas(16) u16 hA[64 * 512];
  __shared__ f32x2 stats[64][8];
  __shared__ f32x2 mufb[64];
  int tid = threadIdx.x;
  int wave = tid >> 6, lane = tid & 63;
  int lrow = lane & 15, lhi = lane >> 4;
  int g0 = blockIdx.x * 2, g1 = g0 + 1;

  const float4* b1v = (const float4*)b1;
  float4 ba = b1v[lane * 2], bb2 = b1v[lane * 2 + 1];
  float bias[8] = {ba.x, ba.y, ba.z, ba.w, bb2.x, bb2.y, bb2.z, bb2.w};

  f32x4 acc[4][4];
  u16x8 bpre[4];

  // ---- graph A ----
  stage_h1<1>(PQ, g0, hA, bias, wave, lane);
  preload_b4(w2p, wave, lane, bpre);
  __syncthreads();
  zero_acc(acc);
  gemm_pipe(hA, w2p, acc, wave, lane, bpre);
  ln_relu8_t<0>(acc, hA, stats, mufb, b2, g, bt, wave, lane, tid, 64);
  __syncthreads();                 // h2n_A visible
  colsum7(hA, 49, tid);            // hsum_A -> rows 49..55
  __syncthreads();                 // colsum A reads of rows 0..48 done
  // ---- graph B ----
  stage_h1<0>(PQ, g1, hA, bias, wave, lane);   // rows 0..48 only
  preload_b4(w2p, wave, lane, bpre);
  __syncthreads();
  zero_acc(acc);
  gemm_pipe(hA, w2p, acc, wave, lane, bpre);
  ln_relu8_t<0>(acc, hA, stats, mufb, b2, g, bt, wave, lane, tid, 49);  // cap: keep hsum_A
  __syncthreads();                 // h2n_B visible
  colsum7(hA, 56, tid);            // hsum_B -> rows 56..62
  preload_b4(w3p, wave, lane, bpre);
  __syncthreads();                 // hsums visible
  // ---- shared 16-row GEMM2 on rows 48..63 ----
  f32x4 acc1[4];
  #pragma unroll
  for (int ct = 0; ct < 4; ++ct){ f32x4 z = {0.f,0.f,0.f,0.f}; acc1[ct] = z; }
  {
    const u16* bb = w3p + ((size_t)(wave * 4) * 64 + lane) * 8;
    u16x8 b_nxt[4];
    #pragma unroll
    for (int kt = 0; kt < 16; ++kt){
      u16x8 a0 = *(const u16x8*)&hA[uidx(48 + lrow, kt * 32 + lhi * 8)];
      if (kt < 15){
        #pragma unroll
        for (int ct = 0; ct < 4; ++ct)
          b_nxt[ct] = *(const u16x8*)&bb[(size_t)(kt + 1) * 16384 + ct * 512];
      }
      #pragma unroll
      for (int ct = 0; ct < 4; ++ct)
        acc1[ct] = mfma16(a0, bpre[ct], acc1[ct]);
      #pragma unroll
      for (int ct = 0; ct < 4; ++ct) bpre[ct] = b_nxt[ct];
    }
  }
  // rows: tr = lhi*4+r; tr 1..7 -> graph A i=tr-1; tr 8..14 -> graph B i=tr-8
  #pragma unroll
  for (int ct = 0; ct < 4; ++ct){
    int c = wave * 64 + ct * 16 + lrow;
    float bb3 = 7.f * b3[c];
    #pragma unroll
    for (int r = 0; r < 4; ++r){
      int tr = lhi * 4 + r;
      if (tr >= 1 && tr <= 14){
        int gg = (tr <= 7) ? g0 : g1;
        int i  = (tr <= 7) ? tr - 1 : tr - 8;
        agg[((size_t)(gg * 7 + i)) * 512 + c] = f2bf(acc1[ct][r] + bb3);
      }
    }
  }
}

// ============ edge pass 1: w3 folded to a vector (w3f = ew3@few) ============
__global__ __launch_bounds__(512, 2) void edge1_kernel(
    const u16* __restrict__ PQ, const u16* __restrict__ w2p,
    const float* __restrict__ b1, const float* __restrict__ b2,
    const float* __restrict__ g, const float* __restrict__ bt,
    const float* __restrict__ w3f, float* __restrict__ out)
{
  __shared__ alignas(16) u16 hA[64 * 512];
  __shared__ f32x2 stats[64][8];
  __shared__ f32x2 mufb[64];
  int gidx = blockIdx.x;
  int tid = threadIdx.x;
  int wave = tid >> 6, lane = tid & 63;

  const float4* b1v = (const float4*)b1;
  float4 ba = b1v[lane * 2], bb2 = b1v[lane * 2 + 1];
  float bias[8] = {ba.x, ba.y, ba.z, ba.w, bb2.x, bb2.y, bb2.z, bb2.w};

  stage_h1<1>(PQ, gidx, hA, bias, wave, lane);
  u16x8 bpre[4];
  preload_b4(w2p, wave, lane, bpre);
  __syncthreads();

  f32x4 acc[4][4];
  zero_acc(acc);
  gemm_pipe(hA, w2p, acc, wave, lane, bpre);
  ln_relu8_t<1>(acc, hA, stats, mufb, b2, g, bt, wave, lane, tid, 64);  // acc := relu(LN)
  head_partial8(acc, w3f, stats, wave, lane);
  __syncthreads();
  if (tid < 49){
    float s = w3f[512];   // eb3.few + feb
    #pragma unroll
    for (int w = 0; w < 8; ++w) s += stats[tid][w][0];
    out[(size_t)gidx * 56 + 7 + tid] = s;
  }
}

// ==== node mega-kernel: r1 -> h2 -> LN -> node2 (+head) -> PQ (pass 2) ====
__global__ __launch_bounds__(512, 2) void node_mega(
    const u16* __restrict__ nodeb, const u16* __restrict__ aggb,
    const u16* __restrict__ nw1p, const u16* __restrict__ nw2p,
    const u16* __restrict__ nw3p, const u16* __restrict__ w1p,
    const float* __restrict__ nb1, const float* __restrict__ nb2,
    const float* __restrict__ ng, const float* __restrict__ nbt,
    const float* __restrict__ nb3, const float* __restrict__ hw,
    const float* __restrict__ hb,
    u16* __restrict__ PQ, float* __restrict__ out)
{
  __shared__ alignas(16) u16 hA[64 * 512];
  __shared__ f32x2 stats[64][8];
  __shared__ f32x2 mufb[64];
  int tid = threadIdx.x;
  int wave = tid >> 6, lane = tid & 63;
  int lrow = lane & 15, lhi = lane >> 4;
  size_t row0 = (size_t)blockIdx.x * 64;

  // r1 = relu([nodeb|aggb] @ nw1 + nb1)  (K=1024, A from global)
  f32x4 acc[4][4];
  zero_acc(acc);
  gemm_k1024_gA(nodeb, aggb, row0, nw1p, acc, wave, lane);
  relu_to_lds(acc, hA, nb1, wave, lane);
  u16x8 bpre[4];
  preload_b4(nw2p, wave, lane, bpre);
  __syncthreads();
  // h2 = r1 @ nw2 (+nb2 in LN) -> LN -> relu -> hA
  zero_acc(acc);
  gemm_pipe(hA, nw2p, acc, wave, lane, bpre);
  ln_relu8_t<0>(acc, hA, stats, mufb, nb2, ng, nbt, wave, lane, tid, 64);
  preload_b4(nw3p, wave, lane, bpre);
  __syncthreads();
  // node2 = h2n @ nw3 + nb3
  zero_acc(acc);
  gemm_pipe(hA, nw3p, acc, wave, lane, bpre);
  add_bias8(acc, nb3, wave, lane);
  __syncthreads();   // all GEMM reads of hA (h2n) done before overwrite
  // node2 -> hA (for PQ GEMMs); head partial
  #pragma unroll
  for (int ct = 0; ct < 4; ++ct){
    int c = wave * 64 + ct * 16 + lrow;
    #pragma unroll
    for (int mt = 0; mt < 4; ++mt)
      #pragma unroll
      for (int r = 0; r < 4; ++r)
        hA[uidx(mt * 16 + lhi * 4 + r, c)] = f2bf(acc[mt][ct][r]);
  }
  head_partial8(acc, hw, stats, wave, lane);
  __syncthreads();   // node2 + stats visible
  if (tid < 64){
    size_t v = row0 + tid;
    float s = hb[0];
    #pragma unroll
    for (int w = 0; w < 8; ++w) s += stats[tid][w][0];
    out[(v / 7) * 56 + (v % 7)] = s;
  }
  // PQ = node2 @ w1p  (N=1024, two 512-col passes; w1p nt=64 -> kt-stride 32768)
  #pragma unroll
  for (int p = 0; p < 2; ++p){
    zero_acc(acc);
    const u16* bbBase = w1p + (((size_t)(p * 32) + wave * 4) * 64 + lane) * 8;
    gemm_pipe_s(hA, bbBase, 32768, acc, lane);
    #pragma unroll
    for (int ct = 0; ct < 4; ++ct){
      int c = p * 512 + wave * 64 + ct * 16 + lrow;
      #pragma unroll
      for (int mt = 0; mt < 4; ++mt)
        #pragma unroll
        for (int r = 0; r < 4; ++r){
          size_t grow = row0 + mt * 16 + lhi * 4 + r;
          PQ[grow * 1024 + c] = f2bf(acc[mt][ct][r]);
        }
    }
  }
}

// gemm64 MODE0 (r5 form): PQ = nodeb @ w1p (pass 1), N=1024 via blockIdx.y slabs.
__global__ __launch_bounds__(256, 2) void gemm64_0(
    const u16* __restrict__ A0, const u16* __restrict__ Bp, u16* __restrict__ Cout)
{
  int tid = threadIdx.x;
  int wave = tid >> 6, lane = tid & 63;
  int lrow = lane & 15, lhi = lane >> 4;
  size_t row0 = (size_t)blockIdx.x * 64;
  int coff = blockIdx.y * 512;
  const u16* bb = Bp + (((size_t)(coff >> 4) + wave * 8) * 64 + lane) * 8;
  f32x4 acc[4][8];
  #pragma unroll
  for (int mt = 0; mt < 4; ++mt)
    #pragma unroll
    for (int ct = 0; ct < 8; ++ct){
      f32x4 z = {0.f, 0.f, 0.f, 0.f};
      acc[mt][ct] = z;
    }
  u16x8 b_cur[8], b_nxt[8];
  #pragma unroll
  for (int ct = 0; ct < 8; ++ct) b_cur[ct] = *(const u16x8*)&bb[ct * 512];
  #pragma unroll
  for (int kt = 0; kt < 16; ++kt){
    u16x8 af[4];
    #pragma unroll
    for (int mt = 0; mt < 4; ++mt)
      af[mt] = *(const u16x8*)&A0[(row0 + mt * 16 + lrow) * 512 + kt * 32 + lhi * 8];
    if (kt < 15){
      #pragma unroll
      for (int ct = 0; ct < 8; ++ct)
        b_nxt[ct] = *(const u16x8*)&bb[((size_t)(kt + 1) * 64 * 64 + ct * 64) * 8];
    }
    __builtin_amdgcn_s_setprio(1);
    #pragma unroll
    for (int ct = 0; ct < 8; ++ct)
      #pragma unroll
      for (int mt = 0; mt < 4; ++mt) acc[mt][ct] = mfma16(af[mt], b_cur[ct], acc[mt][ct]);
    __builtin_amdgcn_s_setprio(0);
    #pragma unroll
    for (int ct = 0; ct < 8; ++ct) b_cur[ct] = b_nxt[ct];
  }
  #pragma unroll
  for (int ct = 0; ct < 8; ++ct){
    int c = coff + wave * 128 + ct * 16 + lrow;
    #pragma unroll
    for (int mt = 0; mt < 4; ++mt)
      #pragma unroll
      for (int r = 0; r < 4; ++r){
        size_t grow = row0 + mt * 16 + lhi * 4 + r;
        Cout[grow * 1024 + c] = f2bf(acc[mt][ct][r]);
      }
  }
}

// w3f[k] = sum_c ew3[k][c]*few[c]  (f32); w3f[512] = eb3.few + feb
__global__ void fold_w3(const float* __restrict__ W3, const float* __restrict__ hw,
                        const float* __restrict__ b3, const float* __restrict__ hb,
                        float* __restrict__ w3f)
{
  int k = blockIdx.x, l = threadIdx.x;
  const float* row = (k < 512) ? (W3 + (size_t)k * 512) : b3;
  float s = 0.f;
  for (int c = l; c < 512; c += 64) s += row[c] * hw[c];
  #pragma unroll
  for (int off = 32; off; off >>= 1) s += __shfl_down(s, off);
  if (l == 0) w3f[k] = (k < 512) ? s : s + hb[0];
}

// Pack f32 weight [K][N] into MFMA B-fragment order (bf16).
__global__ void pack_w(const float* __restrict__ W, u16* __restrict__ dst,
                       int K, int N, int w1mode)
{
  int idx = blockIdx.x * 256 + threadIdx.x;
  int total = (K >> 5) * (N >> 4) * 64;
  if (idx >= total) return;
  int lane = idx & 63;
  int t = idx >> 6;
  int nt = N >> 4;
  int ct = t % nt;
  int kt = t / nt;
  int c  = ct * 16 + (lane & 15);
  int k0 = kt * 32 + (lane >> 4) * 8;
  u16x8 o;
  #pragma unroll
  for (int j = 0; j < 8; ++j){
    int k = k0 + j;
    float v;
    if (w1mode){
      v = (c < 512) ? W[(size_t)k * 512 + c] : W[(size_t)(k + 512) * 512 + (c - 512)];
    } else {
      v = W[(size_t)k * N + c];
    }
    o[j] = f2bf(v);
  }
  *(u16x8*)&dst[(size_t)idx * 8] = o;
}

__global__ void cast_node(const float* __restrict__ src, u16* __restrict__ dst, int n8){
  int idx = blockIdx.x * 256 + threadIdx.x;
  if (idx >= n8) return;
  const float4* s = (const float4*)src;
  float4 a = s[(size_t)idx * 2], b = s[(size_t)idx * 2 + 1];
  u16x8 o;
  o[0] = f2bf(a.x); o[1] = f2bf(a.y); o[2] = f2bf(a.z); o[3] = f2bf(a.w);
  o[4] = f2bf(b.x); o[5] = f2bf(b.y); o[6] = f2bf(b.z); o[7] = f2bf(b.w);
  *(u16x8*)&dst[(size_t)idx * 8] = o;
}

extern "C" void kernel_launch(void* const* d_in, const int* in_sizes, int n_in,
                              void* d_out, int out_size, void* d_ws, size_t ws_size,
                              hipStream_t stream)
{
  (void)in_sizes; (void)n_in; (void)out_size; (void)ws_size;
  const float* states = (const float*)d_in[0];
  const float* ew1 = (const float*)d_in[1];
  const float* eb1 = (const float*)d_in[2];
  const float* ew2 = (const float*)d_in[3];
  const float* eb2 = (const float*)d_in[4];
  const float* eg  = (const float*)d_in[5];
  const float* ebt = (const float*)d_in[6];
  const float* ew3 = (const float*)d_in[7];
  const float* eb3 = (const float*)d_in[8];
  const float* nw1 = (const float*)d_in[9];
  const float* nb1 = (const float*)d_in[10];
  const float* nw2 = (const float*)d_in[11];
  const float* nb2 = (const float*)d_in[12];
  const float* ng  = (const float*)d_in[13];
  const float* nbt = (const float*)d_in[14];
  const float* nw3 = (const float*)d_in[15];
  const float* nb3 = (const float*)d_in[16];
  const float* fnw = (const float*)d_in[17];
  const float* fnb = (const float*)d_in[18];
  const float* few = (const float*)d_in[19];
  const float* feb = (const float*)d_in[20];
  float* out = (float*)d_out;

  char* ws = (char*)d_ws;
  size_t off = 0;
  auto alloc = [&](size_t bytes) -> void* {
    void* p = ws + off;
    off += (bytes + 255) & ~(size_t)255;
    return p;
  };
  const size_t NV = 28672;  // B*n
  u16* PQ    = (u16*)alloc(NV * 1024 * 2);   // [NV][P(512)|Q(512)] bf16
  u16* nodeb = (u16*)alloc(NV * 512 * 2);
  u16* aggb  = (u16*)alloc(NV * 512 * 2);
  u16* w1p   = (u16*)alloc(512 * 1024 * 2);
  u16* nw1p  = (u16*)alloc(1024 * 512 * 2);
  u16* w2p   = (u16*)alloc(512 * 512 * 2);
  u16* w3p   = (u16*)alloc(512 * 512 * 2);
  u16* nw2p  = (u16*)alloc(512 * 512 * 2);
  u16* nw3p  = (u16*)alloc(512 * 512 * 2);
  float* w3f = (float*)alloc(513 * 4);

  pack_w<<<256, 256, 0, stream>>>(ew1, w1p, 512, 1024, 1);
  pack_w<<<256, 256, 0, stream>>>(nw1, nw1p, 1024, 512, 0);
  pack_w<<<128, 256, 0, stream>>>(ew2, w2p, 512, 512, 0);
  pack_w<<<128, 256, 0, stream>>>(ew3, w3p, 512, 512, 0);
  pack_w<<<128, 256, 0, stream>>>(nw2, nw2p, 512, 512, 0);
  pack_w<<<128, 256, 0, stream>>>(nw3, nw3p, 512, 512, 0);
  fold_w3<<<513, 64, 0, stream>>>(ew3, few, eb3, feb, w3f);
  cast_node<<<7168, 256, 0, stream>>>(states, nodeb, (int)(NV * 512 / 8));

  // Pass 1
  gemm64_0<<<dim3(448, 2), 256, 0, stream>>>(nodeb, w1p, PQ);
  edge0_kernel<<<2048, 512, 0, stream>>>(PQ, w2p, w3p, eb1, eb2, eg, ebt, eb3, aggb);
  // Node update + head + PQ for pass 2 (fused)
  node_mega<<<448, 512, 0, stream>>>(nodeb, aggb, nw1p, nw2p, nw3p, w1p,
                                     nb1, nb2, ng, nbt, nb3, fnw, fnb, PQ, out);
  // Pass 2 edge head
  edge1_kernel<<<4096, 512, 0, stream>>>(PQ, w2p, eb1, eb2, eg, ebt, w3f, out);
}

// Round 14
// 592.651 us; speedup vs baseline: 1.2247x; 1.2247x over previous
//
#include <hip/hip_runtime.h>

#define LN_EPS 1e-5f

typedef unsigned short u16;
typedef u16 u16x8 __attribute__((ext_vector_type(8)));
typedef __bf16 bf16x8 __attribute__((ext_vector_type(8)));
typedef float f32x4 __attribute__((ext_vector_type(4)));
typedef float f32x2 __attribute__((ext_vector_type(2)));

__device__ __forceinline__ u16 f2bf(float f){
  return __builtin_bit_cast(u16, (__bf16)f);
}
__device__ __forceinline__ float bf2f(u16 b){
  return (float)__builtin_bit_cast(__bf16, b);
}
__device__ __forceinline__ f32x4 mfma16(u16x8 a, u16x8 b, f32x4 c){
  return __builtin_amdgcn_mfma_f32_16x16x32_bf16(
      __builtin_bit_cast(bf16x8, a), __builtin_bit_cast(bf16x8, b), c, 0, 0, 0);
}
// LDS h-tile: [64 rows][512 k] bf16, XOR swizzle on k (8-elem granules)
__device__ __forceinline__ int uidx(int row, int k){
  return row * 512 + (k ^ ((row & 7) << 3));
}

__device__ __forceinline__ void zero_acc(f32x4 (&acc)[4][4]){
  #pragma unroll
  for (int mt = 0; mt < 4; ++mt)
    #pragma unroll
    for (int ct = 0; ct < 4; ++ct){
      f32x4 z = {0.f, 0.f, 0.f, 0.f};
      acc[mt][ct] = z;
    }
}

// Issue first kt's 4 B-fragment loads BEFORE the preceding barrier (in flight
// across s_barrier; hides cold-start L2 latency).
__device__ __forceinline__ void preload_b4(const u16* __restrict__ Bp, int wave, int lane,
                                           u16x8 (&b)[4]){
  const u16* bb = Bp + ((size_t)(wave * 4) * 64 + lane) * 8;
  #pragma unroll
  for (int ct = 0; ct < 4; ++ct) b[ct] = *(const u16x8*)&bb[ct * 512];
}

// GEMM, A from LDS (64 rows), B from global (N=512 packing, kt-stride 16384),
// 1-deep register prefetch (~88 VGPR). b_cur arrives preloaded.
__device__ __forceinline__ void gemm_pipe(const u16* hA, const u16* __restrict__ Bp,
                                          f32x4 (&acc)[4][4], int wave, int lane,
                                          u16x8 (&b_cur)[4]){
  int lrow = lane & 15, lhi = lane >> 4;
  const u16* bb = Bp + ((size_t)(wave * 4) * 64 + lane) * 8;
  u16x8 b_nxt[4], a[4];
  #pragma unroll
  for (int kt = 0; kt < 16; ++kt){
    #pragma unroll
    for (int mt = 0; mt < 4; ++mt)
      a[mt] = *(const u16x8*)&hA[uidx(mt * 16 + lrow, kt * 32 + lhi * 8)];
    if (kt < 15){
      #pragma unroll
      for (int ct = 0; ct < 4; ++ct)
        b_nxt[ct] = *(const u16x8*)&bb[(size_t)(kt + 1) * 16384 + ct * 512];
    }
    __builtin_amdgcn_s_setprio(1);
    #pragma unroll
    for (int ct = 0; ct < 4; ++ct)
      #pragma unroll
      for (int mt = 0; mt < 4; ++mt)
        acc[mt][ct] = mfma16(a[mt], b_cur[ct], acc[mt][ct]);
    __builtin_amdgcn_s_setprio(0);
    #pragma unroll
    for (int ct = 0; ct < 4; ++ct) b_cur[ct] = b_nxt[ct];
  }
}

// K=1024 GEMM, A rows from TWO global sources (nodeb | aggb), B = nw1p (N16=32
// packing, kt-stride 16384, KT=32).
__device__ __forceinline__ void gemm_k1024_gA(const u16* __restrict__ A0,
                                              const u16* __restrict__ A1, size_t row0,
                                              const u16* __restrict__ Bp,
                                              f32x4 (&acc)[4][4], int wave, int lane){
  int lrow = lane & 15, lhi = lane >> 4;
  const u16* bb = Bp + ((size_t)(wave * 4) * 64 + lane) * 8;
  const u16* a0 = A0 + (row0 + lrow) * 512 + lhi * 8;
  const u16* a1 = A1 + (row0 + lrow) * 512 + lhi * 8;
  u16x8 b_cur[4], b_nxt[4], a[4];
  #pragma unroll
  for (int ct = 0; ct < 4; ++ct) b_cur[ct] = *(const u16x8*)&bb[ct * 512];
  #pragma unroll
  for (int kt = 0; kt < 32; ++kt){
    const u16* ab = (kt < 16) ? a0 : a1;
    int kk = (kt & 15) * 32;
    #pragma unroll
    for (int mt = 0; mt < 4; ++mt)
      a[mt] = *(const u16x8*)&ab[mt * 8192 + kk];
    if (kt < 31){
      #pragma unroll
      for (int ct = 0; ct < 4; ++ct)
        b_nxt[ct] = *(const u16x8*)&bb[(size_t)(kt + 1) * 16384 + ct * 512];
    }
    __builtin_amdgcn_s_setprio(1);
    #pragma unroll
    for (int ct = 0; ct < 4; ++ct)
      #pragma unroll
      for (int mt = 0; mt < 4; ++mt)
        acc[mt][ct] = mfma16(a[mt], b_cur[ct], acc[mt][ct]);
    __builtin_amdgcn_s_setprio(0);
    #pragma unroll
    for (int ct = 0; ct < 4; ++ct) b_cur[ct] = b_nxt[ct];
  }
}

// GEMM over hA with custom B base/kt-stride (for N=1024 w1p packing).
__device__ __forceinline__ void gemm_pipe_s(const u16* hA, const u16* __restrict__ bbBase,
                                            int ktStride, f32x4 (&acc)[4][4],
                                            int lane){
  int lrow = lane & 15, lhi = lane >> 4;
  u16x8 b_cur[4], b_nxt[4], a[4];
  #pragma unroll
  for (int ct = 0; ct < 4; ++ct) b_cur[ct] = *(const u16x8*)&bbBase[ct * 512];
  #pragma unroll
  for (int kt = 0; kt < 16; ++kt){
    #pragma unroll
    for (int mt = 0; mt < 4; ++mt)
      a[mt] = *(const u16x8*)&hA[uidx(mt * 16 + lrow, kt * 32 + lhi * 8)];
    if (kt < 15){
      #pragma unroll
      for (int ct = 0; ct < 4; ++ct)
        b_nxt[ct] = *(const u16x8*)&bbBase[(size_t)(kt + 1) * ktStride + ct * 512];
    }
    __builtin_amdgcn_s_setprio(1);
    #pragma unroll
    for (int ct = 0; ct < 4; ++ct)
      #pragma unroll
      for (int mt = 0; mt < 4; ++mt)
        acc[mt][ct] = mfma16(a[mt], b_cur[ct], acc[mt][ct]);
    __builtin_amdgcn_s_setprio(0);
    #pragma unroll
    for (int ct = 0; ct < 4; ++ct) b_cur[ct] = b_nxt[ct];
  }
}

__device__ __forceinline__ void add_bias8(f32x4 (&acc)[4][4], const float* __restrict__ b,
                                          int wave, int lane){
  int lrow = lane & 15;
  #pragma unroll
  for (int ct = 0; ct < 4; ++ct){
    float bb = b[wave * 64 + ct * 16 + lrow];
    #pragma unroll
    for (int mt = 0; mt < 4; ++mt)
      #pragma unroll
      for (int r = 0; r < 4; ++r) acc[mt][ct][r] += bb;
  }
}

// acc += bias; relu; write bf16 into hA (swizzled). (r1 stage of node MLP.)
__device__ __forceinline__ void relu_to_lds(f32x4 (&acc)[4][4], u16* hA,
                                            const float* __restrict__ b,
                                            int wave, int lane){
  int lrow = lane & 15, lhi = lane >> 4;
  #pragma unroll
  for (int ct = 0; ct < 4; ++ct){
    int c = wave * 64 + ct * 16 + lrow;
    float bb = b[c];
    #pragma unroll
    for (int mt = 0; mt < 4; ++mt)
      #pragma unroll
      for (int r = 0; r < 4; ++r){
        int row = mt * 16 + lhi * 4 + r;
        hA[uidx(row, c)] = f2bf(fmaxf(acc[mt][ct][r] + bb, 0.f));
      }
  }
}

// acc += b2; LayerNorm over 512 cols per row; relu.
// TO_ACC=0: write bf16 into hA (swizzled); TO_ACC=1: result into acc.
template<int TO_ACC>
__device__ __forceinline__ void ln_relu8_t(f32x4 (&acc)[4][4], u16* hA,
    f32x2 (*stats)[8], f32x2* mufb,
    const float* __restrict__ b2, const float* __restrict__ g, const float* __restrict__ bt,
    int wave, int lane, int tid)
{
  int lrow = lane & 15, lhi = lane >> 4;
  float s1[4][4], s2[4][4];
  #pragma unroll
  for (int mt = 0; mt < 4; ++mt)
    #pragma unroll
    for (int r = 0; r < 4; ++r){ s1[mt][r] = 0.f; s2[mt][r] = 0.f; }
  #pragma unroll
  for (int ct = 0; ct < 4; ++ct){
    int c = wave * 64 + ct * 16 + lrow;
    float bb = b2[c];
    #pragma unroll
    for (int mt = 0; mt < 4; ++mt)
      #pragma unroll
      for (int r = 0; r < 4; ++r){
        float x = acc[mt][ct][r] + bb;
        acc[mt][ct][r] = x;
        s1[mt][r] += x; s2[mt][r] += x * x;
      }
  }
  #pragma unroll
  for (int off = 1; off < 16; off <<= 1){
    #pragma unroll
    for (int mt = 0; mt < 4; ++mt)
      #pragma unroll
      for (int r = 0; r < 4; ++r){
        s1[mt][r] += __shfl_xor(s1[mt][r], off);
        s2[mt][r] += __shfl_xor(s2[mt][r], off);
      }
  }
  float sa1 = 0.f, sa2 = 0.f;
  #pragma unroll
  for (int mt = 0; mt < 4; ++mt)
    #pragma unroll
    for (int r = 0; r < 4; ++r)
      if (lrow == mt * 4 + r){ sa1 = s1[mt][r]; sa2 = s2[mt][r]; }
  int rowa = (lrow >> 2) * 16 + lhi * 4 + (lrow & 3);
  f32x2 pa = {sa1, sa2};
  stats[rowa][wave] = pa;
  __syncthreads();              // also: all waves done reading hA (prev GEMM)
  if (tid < 64){
    float a = 0.f, b = 0.f;
    #pragma unroll
    for (int w = 0; w < 8; ++w){ a += stats[tid][w][0]; b += stats[tid][w][1]; }
    float mu  = a * (1.f / 512.f);
    float var = b * (1.f / 512.f) - mu * mu;
    f32x2 mr = {mu, rsqrtf(fmaxf(var, 0.f) + LN_EPS)};
    mufb[tid] = mr;
  }
  __syncthreads();
  float gv[4], btv[4];
  #pragma unroll
  for (int ct = 0; ct < 4; ++ct){
    int c = wave * 64 + ct * 16 + lrow;
    gv[ct] = g[c]; btv[ct] = bt[c];
  }
  #pragma unroll
  for (int mt = 0; mt < 4; ++mt)
    #pragma unroll
    for (int r = 0; r < 4; ++r){
      int row = mt * 16 + lhi * 4 + r;
      f32x2 mr = mufb[row];
      #pragma unroll
      for (int ct = 0; ct < 4; ++ct){
        int c = wave * 64 + ct * 16 + lrow;
        float x = (acc[mt][ct][r] - mr[0]) * mr[1] * gv[ct] + btv[ct];
        if (TO_ACC) acc[mt][ct][r] = fmaxf(x, 0.f);
        else        hA[uidx(row, c)] = f2bf(fmaxf(x, 0.f));
      }
    }
  // TO_ACC=0 caller: barrier before any cross-thread hA read.
}

// dot each row with weight vector w; per-wave partial -> stats[row][wave].x
__device__ __forceinline__ void head_partial8(f32x4 (&acc)[4][4], const float* __restrict__ w,
                                              f32x2 (*stats)[8], int wave, int lane)
{
  int lrow = lane & 15, lhi = lane >> 4;
  float hs[4][4];
  #pragma unroll
  for (int mt = 0; mt < 4; ++mt)
    #pragma unroll
    for (int r = 0; r < 4; ++r) hs[mt][r] = 0.f;
  #pragma unroll
  for (int ct = 0; ct < 4; ++ct){
    int c = wave * 64 + ct * 16 + lrow;
    float f = w[c];
    #pragma unroll
    for (int mt = 0; mt < 4; ++mt)
      #pragma unroll
      for (int r = 0; r < 4; ++r) hs[mt][r] += acc[mt][ct][r] * f;
  }
  #pragma unroll
  for (int off = 1; off < 16; off <<= 1)
    #pragma unroll
    for (int mt = 0; mt < 4; ++mt)
      #pragma unroll
      for (int r = 0; r < 4; ++r) hs[mt][r] += __shfl_xor(hs[mt][r], off);
  float sa = 0.f;
  #pragma unroll
  for (int mt = 0; mt < 4; ++mt)
    #pragma unroll
    for (int r = 0; r < 4; ++r)
      if (lrow == mt * 4 + r) sa = hs[mt][r];
  int rowa = (lrow >> 2) * 16 + lhi * 4 + (lrow & 3);
  f32x2 pa = {sa, 0.f};
  stats[rowa][wave] = pa;
}

// Staging: h1 = relu(P[i]+Q[j]+b1) into hA rows 0..48 (+ zero pad rows 49..63).
__device__ __forceinline__ void stage_h1(const u16* __restrict__ PQ, int gg, u16* hA,
                                         const float* bias, int wave, int lane){
  const u16* Pg = PQ + (size_t)gg * 7 * 1024;
  u16x8 pA, qA, pB, qB;
  {
    int e = wave;
    int i = e / 7, j = e % 7;
    pA = *(const u16x8*)&Pg[(size_t)i * 1024 + lane * 8];
    qA = *(const u16x8*)&Pg[(size_t)j * 1024 + 512 + lane * 8];
  }
  #pragma unroll
  for (int it = 0; it < 8; ++it){
    int e = it * 8 + wave;
    if (it < 7){
      int e2 = e + 8;
      if (e2 < 49){
        int i = e2 / 7, j = e2 % 7;
        pB = *(const u16x8*)&Pg[(size_t)i * 1024 + lane * 8];
        qB = *(const u16x8*)&Pg[(size_t)j * 1024 + 512 + lane * 8];
      }
    }
    u16x8 o;
    if (e < 49){
      #pragma unroll
      for (int u = 0; u < 8; ++u)
        o[u] = f2bf(fmaxf(bf2f(pA[u]) + bf2f(qA[u]) + bias[u], 0.f));
    } else {
      #pragma unroll
      for (int u = 0; u < 8; ++u) o[u] = 0;
    }
    *(u16x8*)&hA[uidx(e, lane * 8)] = o;
    pA = pB; qA = qB;
  }
}

// ======== edge pass 0 (r12 single-graph form, measured 68 VGPR clean) ========
// agg[i] = (sum_j h2n[i,j]) @ w3 + 7*b3: h2n rows 0..48; column-sums into pad
// rows 49..55; 16-row GEMM on rows 48..63.
__global__ __launch_bounds__(512, 2) void edge0_kernel(
    const u16* __restrict__ PQ, const u16* __restrict__ w2p, const u16* __restrict__ w3p,
    const float* __restrict__ b1, const float* __restrict__ b2,
    const float* __restrict__ g, const float* __restrict__ bt, const float* __restrict__ b3,
    u16* __restrict__ agg)
{
  __shared__ alignas(16) u16 hA[64 * 512];
  __shared__ f32x2 stats[64][8];
  __shared__ f32x2 mufb[64];
  int gidx = blockIdx.x;
  int tid = threadIdx.x;
  int wave = tid >> 6, lane = tid & 63;
  int lrow = lane & 15, lhi = lane >> 4;

  const float4* b1v = (const float4*)b1;
  float4 ba = b1v[lane * 2], bb2 = b1v[lane * 2 + 1];
  float bias[8] = {ba.x, ba.y, ba.z, ba.w, bb2.x, bb2.y, bb2.z, bb2.w};

  stage_h1(PQ, gidx, hA, bias, wave, lane);
  u16x8 bpre[4];
  preload_b4(w2p, wave, lane, bpre);
  __syncthreads();

  f32x4 acc[4][4];
  zero_acc(acc);
  gemm_pipe(hA, w2p, acc, wave, lane, bpre);
  ln_relu8_t<0>(acc, hA, stats, mufb, b2, g, bt, wave, lane, tid);
  preload_b4(w3p, wave, lane, bpre);  // in flight across the barrier
  __syncthreads();                    // h2n rows 0..48 visible
  // column sums: hsum[i][c] = sum_j h2n[7i+j][c] -> pad rows 49..55 (bf16)
  {
    int c = tid;   // 0..511
    #pragma unroll
    for (int i = 0; i < 7; ++i){
      float s = 0.f;
      #pragma unroll
      for (int j = 0; j < 7; ++j)
        s += bf2f(hA[uidx(7 * i + j, c)]);
      hA[uidx(49 + i, c)] = f2bf(s);   // rows 49..55 disjoint from reads (0..48)
    }
  }
  __syncthreads();                    // hsum visible
  // 16-row GEMM: A = hA rows 48..63 (49..55 = hsum; others ignored)
  f32x4 acc1[4];
  #pragma unroll
  for (int ct = 0; ct < 4; ++ct){ f32x4 z = {0.f,0.f,0.f,0.f}; acc1[ct] = z; }
  {
    const u16* bb = w3p + ((size_t)(wave * 4) * 64 + lane) * 8;
    u16x8 b_nxt[4];
    #pragma unroll
    for (int kt = 0; kt < 16; ++kt){
      u16x8 a0 = *(const u16x8*)&hA[uidx(48 + lrow, kt * 32 + lhi * 8)];
      if (kt < 15){
        #pragma unroll
        for (int ct = 0; ct < 4; ++ct)
          b_nxt[ct] = *(const u16x8*)&bb[(size_t)(kt + 1) * 16384 + ct * 512];
      }
      #pragma unroll
      for (int ct = 0; ct < 4; ++ct)
        acc1[ct] = mfma16(a0, bpre[ct], acc1[ct]);
      #pragma unroll
      for (int ct = 0; ct < 4; ++ct) bpre[ct] = b_nxt[ct];
    }
  }
  // write agg rows: tile row tr = lhi*4+r; global row 48+tr; i = tr-1 in [0,7)
  #pragma unroll
  for (int ct = 0; ct < 4; ++ct){
    int c = wave * 64 + ct * 16 + lrow;
    float bb3 = 7.f * b3[c];
    #pragma unroll
    for (int r = 0; r < 4; ++r){
      int tr = lhi * 4 + r;
      if (tr >= 1 && tr <= 7){
        int i = tr - 1;
        agg[((size_t)(gidx * 7 + i)) * 512 + c] = f2bf(acc1[ct][r] + bb3);
      }
    }
  }
}

// ============ edge pass 1: w3 folded to a vector (w3f = ew3@few) ============
__global__ __launch_bounds__(512, 2) void edge1_kernel(
    const u16* __restrict__ PQ, const u16* __restrict__ w2p,
    const float* __restrict__ b1, const float* __restrict__ b2,
    const float* __restrict__ g, const float* __restrict__ bt,
    const float* __restrict__ w3f, float* __restrict__ out)
{
  __shared__ alignas(16) u16 hA[64 * 512];
  __shared__ f32x2 stats[64][8];
  __shared__ f32x2 mufb[64];
  int gidx = blockIdx.x;
  int tid = threadIdx.x;
  int wave = tid >> 6, lane = tid & 63;

  const float4* b1v = (const float4*)b1;
  float4 ba = b1v[lane * 2], bb2 = b1v[lane * 2 + 1];
  float bias[8] = {ba.x, ba.y, ba.z, ba.w, bb2.x, bb2.y, bb2.z, bb2.w};

  stage_h1(PQ, gidx, hA, bias, wave, lane);
  u16x8 bpre[4];
  preload_b4(w2p, wave, lane, bpre);
  __syncthreads();

  f32x4 acc[4][4];
  zero_acc(acc);
  gemm_pipe(hA, w2p, acc, wave, lane, bpre);
  ln_relu8_t<1>(acc, hA, stats, mufb, b2, g, bt, wave, lane, tid);  // acc := relu(LN)
  head_partial8(acc, w3f, stats, wave, lane);
  __syncthreads();
  if (tid < 49){
    float s = w3f[512];   // eb3.few + feb
    #pragma unroll
    for (int w = 0; w < 8; ++w) s += stats[tid][w][0];
    out[(size_t)gidx * 56 + 7 + tid] = s;
  }
}

// ==== node mega-kernel: r1 -> h2 -> LN -> node2 (+head) -> PQ (pass 2) ====
__global__ __launch_bounds__(512, 2) void node_mega(
    const u16* __restrict__ nodeb, const u16* __restrict__ aggb,
    const u16* __restrict__ nw1p, const u16* __restrict__ nw2p,
    const u16* __restrict__ nw3p, const u16* __restrict__ w1p,
    const float* __restrict__ nb1, const float* __restrict__ nb2,
    const float* __restrict__ ng, const float* __restrict__ nbt,
    const float* __restrict__ nb3, const float* __restrict__ hw,
    const float* __restrict__ hb,
    u16* __restrict__ PQ, float* __restrict__ out)
{
  __shared__ alignas(16) u16 hA[64 * 512];
  __shared__ f32x2 stats[64][8];
  __shared__ f32x2 mufb[64];
  int tid = threadIdx.x;
  int wave = tid >> 6, lane = tid & 63;
  int lrow = lane & 15, lhi = lane >> 4;
  size_t row0 = (size_t)blockIdx.x * 64;

  // r1 = relu([nodeb|aggb] @ nw1 + nb1)  (K=1024, A from global)
  f32x4 acc[4][4];
  zero_acc(acc);
  gemm_k1024_gA(nodeb, aggb, row0, nw1p, acc, wave, lane);
  relu_to_lds(acc, hA, nb1, wave, lane);
  u16x8 bpre[4];
  preload_b4(nw2p, wave, lane, bpre);
  __syncthreads();
  // h2 = r1 @ nw2 (+nb2 in LN) -> LN -> relu -> hA
  zero_acc(acc);
  gemm_pipe(hA, nw2p, acc, wave, lane, bpre);
  ln_relu8_t<0>(acc, hA, stats, mufb, nb2, ng, nbt, wave, lane, tid);
  preload_b4(nw3p, wave, lane, bpre);
  __syncthreads();
  // node2 = h2n @ nw3 + nb3
  zero_acc(acc);
  gemm_pipe(hA, nw3p, acc, wave, lane, bpre);
  add_bias8(acc, nb3, wave, lane);
  __syncthreads();   // all GEMM reads of hA (h2n) done before overwrite
  // node2 -> hA (for PQ GEMMs); head partial
  #pragma unroll
  for (int ct = 0; ct < 4; ++ct){
    int c = wave * 64 + ct * 16 + lrow;
    #pragma unroll
    for (int mt = 0; mt < 4; ++mt)
      #pragma unroll
      for (int r = 0; r < 4; ++r)
        hA[uidx(mt * 16 + lhi * 4 + r, c)] = f2bf(acc[mt][ct][r]);
  }
  head_partial8(acc, hw, stats, wave, lane);
  __syncthreads();   // node2 + stats visible
  if (tid < 64){
    size_t v = row0 + tid;
    float s = hb[0];
    #pragma unroll
    for (int w = 0; w < 8; ++w) s += stats[tid][w][0];
    out[(v / 7) * 56 + (v % 7)] = s;
  }
  // PQ = node2 @ w1p  (N=1024, two 512-col passes; w1p nt=64 -> kt-stride 32768)
  #pragma unroll
  for (int p = 0; p < 2; ++p){
    zero_acc(acc);
    const u16* bbBase = w1p + (((size_t)(p * 32) + wave * 4) * 64 + lane) * 8;
    gemm_pipe_s(hA, bbBase, 32768, acc, lane);
    #pragma unroll
    for (int ct = 0; ct < 4; ++ct){
      int c = p * 512 + wave * 64 + ct * 16 + lrow;
      #pragma unroll
      for (int mt = 0; mt < 4; ++mt)
        #pragma unroll
        for (int r = 0; r < 4; ++r){
          size_t grow = row0 + mt * 16 + lhi * 4 + r;
          PQ[grow * 1024 + c] = f2bf(acc[mt][ct][r]);
        }
    }
  }
}

// gemm64 MODE0 (r5 form): PQ = nodeb @ w1p (pass 1), N=1024 via blockIdx.y slabs.
__global__ __launch_bounds__(256, 2) void gemm64_0(
    const u16* __restrict__ A0, const u16* __restrict__ Bp, u16* __restrict__ Cout)
{
  int tid = threadIdx.x;
  int wave = tid >> 6, lane = tid & 63;
  int lrow = lane & 15, lhi = lane >> 4;
  size_t row0 = (size_t)blockIdx.x * 64;
  int coff = blockIdx.y * 512;
  const u16* bb = Bp + (((size_t)(coff >> 4) + wave * 8) * 64 + lane) * 8;
  f32x4 acc[4][8];
  #pragma unroll
  for (int mt = 0; mt < 4; ++mt)
    #pragma unroll
    for (int ct = 0; ct < 8; ++ct){
      f32x4 z = {0.f, 0.f, 0.f, 0.f};
      acc[mt][ct] = z;
    }
  u16x8 b_cur[8], b_nxt[8];
  #pragma unroll
  for (int ct = 0; ct < 8; ++ct) b_cur[ct] = *(const u16x8*)&bb[ct * 512];
  #pragma unroll
  for (int kt = 0; kt < 16; ++kt){
    u16x8 af[4];
    #pragma unroll
    for (int mt = 0; mt < 4; ++mt)
      af[mt] = *(const u16x8*)&A0[(row0 + mt * 16 + lrow) * 512 + kt * 32 + lhi * 8];
    if (kt < 15){
      #pragma unroll
      for (int ct = 0; ct < 8; ++ct)
        b_nxt[ct] = *(const u16x8*)&bb[((size_t)(kt + 1) * 64 * 64 + ct * 64) * 8];
    }
    __builtin_amdgcn_s_setprio(1);
    #pragma unroll
    for (int ct = 0; ct < 8; ++ct)
      #pragma unroll
      for (int mt = 0; mt < 4; ++mt) acc[mt][ct] = mfma16(af[mt], b_cur[ct], acc[mt][ct]);
    __builtin_amdgcn_s_setprio(0);
    #pragma unroll
    for (int ct = 0; ct < 8; ++ct) b_cur[ct] = b_nxt[ct];
  }
  #pragma unroll
  for (int ct = 0; ct < 8; ++ct){
    int c = coff + wave * 128 + ct * 16 + lrow;
    #pragma unroll
    for (int mt = 0; mt < 4; ++mt)
      #pragma unroll
      for (int r = 0; r < 4; ++r){
        size_t grow = row0 + mt * 16 + lhi * 4 + r;
        Cout[grow * 1024 + c] = f2bf(acc[mt][ct][r]);
      }
  }
}

// w3f[k] = sum_c ew3[k][c]*few[c]  (f32); w3f[512] = eb3.few + feb
__global__ void fold_w3(const float* __restrict__ W3, const float* __restrict__ hw,
                        const float* __restrict__ b3, const float* __restrict__ hb,
                        float* __restrict__ w3f)
{
  int k = blockIdx.x, l = threadIdx.x;
  const float* row = (k < 512) ? (W3 + (size_t)k * 512) : b3;
  float s = 0.f;
  for (int c = l; c < 512; c += 64) s += row[c] * hw[c];
  #pragma unroll
  for (int off = 32; off; off >>= 1) s += __shfl_down(s, off);
  if (l == 0) w3f[k] = (k < 512) ? s : s + hb[0];
}

// Pack f32 weight [K][N] into MFMA B-fragment order (bf16).
__global__ void pack_w(const float* __restrict__ W, u16* __restrict__ dst,
                       int K, int N, int w1mode)
{
  int idx = blockIdx.x * 256 + threadIdx.x;
  int total = (K >> 5) * (N >> 4) * 64;
  if (idx >= total) return;
  int lane = idx & 63;
  int t = idx >> 6;
  int nt = N >> 4;
  int ct = t % nt;
  int kt = t / nt;
  int c  = ct * 16 + (lane & 15);
  int k0 = kt * 32 + (lane >> 4) * 8;
  u16x8 o;
  #pragma unroll
  for (int j = 0; j < 8; ++j){
    int k = k0 + j;
    float v;
    if (w1mode){
      v = (c < 512) ? W[(size_t)k * 512 + c] : W[(size_t)(k + 512) * 512 + (c - 512)];
    } else {
      v = W[(size_t)k * N + c];
    }
    o[j] = f2bf(v);
  }
  *(u16x8*)&dst[(size_t)idx * 8] = o;
}

__global__ void cast_node(const float* __restrict__ src, u16* __restrict__ dst, int n8){
  int idx = blockIdx.x * 256 + threadIdx.x;
  if (idx >= n8) return;
  const float4* s = (const float4*)src;
  float4 a = s[(size_t)idx * 2], b = s[(size_t)idx * 2 + 1];
  u16x8 o;
  o[0] = f2bf(a.x); o[1] = f2bf(a.y); o[2] = f2bf(a.z); o[3] = f2bf(a.w);
  o[4] = f2bf(b.x); o[5] = f2bf(b.y); o[6] = f2bf(b.z); o[7] = f2bf(b.w);
  *(u16x8*)&dst[(size_t)idx * 8] = o;
}

extern "C" void kernel_launch(void* const* d_in, const int* in_sizes, int n_in,
                              void* d_out, int out_size, void* d_ws, size_t ws_size,
                              hipStream_t stream)
{
  (void)in_sizes; (void)n_in; (void)out_size; (void)ws_size;
  const float* states = (const float*)d_in[0];
  const float* ew1 = (const float*)d_in[1];
  const float* eb1 = (const float*)d_in[2];
  const float* ew2 = (const float*)d_in[3];
  const float* eb2 = (const float*)d_in[4];
  const float* eg  = (const float*)d_in[5];
  const float* ebt = (const float*)d_in[6];
  const float* ew3 = (const float*)d_in[7];
  const float* eb3 = (const float*)d_in[8];
  const float* nw1 = (const float*)d_in[9];
  const float* nb1 = (const float*)d_in[10];
  const float* nw2 = (const float*)d_in[11];
  const float* nb2 = (const float*)d_in[12];
  const float* ng  = (const float*)d_in[13];
  const float* nbt = (const float*)d_in[14];
  const float* nw3 = (const float*)d_in[15];
  const float* nb3 = (const float*)d_in[16];
  const float* fnw = (const float*)d_in[17];
  const float* fnb = (const float*)d_in[18];
  const float* few = (const float*)d_in[19];
  const float* feb = (const float*)d_in[20];
  float* out = (float*)d_out;

  char* ws = (char*)d_ws;
  size_t off = 0;
  auto alloc = [&](size_t bytes) -> void* {
    void* p = ws + off;
    off += (bytes + 255) & ~(size_t)255;
    return p;
  };
  const size_t NV = 28672;  // B*n
  u16* PQ    = (u16*)alloc(NV * 1024 * 2);   // [NV][P(512)|Q(512)] bf16
  u16* nodeb = (u16*)alloc(NV * 512 * 2);
  u16* aggb  = (u16*)alloc(NV * 512 * 2);
  u16* w1p   = (u16*)alloc(512 * 1024 * 2);
  u16* nw1p  = (u16*)alloc(1024 * 512 * 2);
  u16* w2p   = (u16*)alloc(512 * 512 * 2);
  u16* w3p   = (u16*)alloc(512 * 512 * 2);
  u16* nw2p  = (u16*)alloc(512 * 512 * 2);
  u16* nw3p  = (u16*)alloc(512 * 512 * 2);
  float* w3f = (float*)alloc(513 * 4);

  pack_w<<<256, 256, 0, stream>>>(ew1, w1p, 512, 1024, 1);
  pack_w<<<256, 256, 0, stream>>>(nw1, nw1p, 1024, 512, 0);
  pack_w<<<128, 256, 0, stream>>>(ew2, w2p, 512, 512, 0);
  pack_w<<<128, 256, 0, stream>>>(ew3, w3p, 512, 512, 0);
  pack_w<<<128, 256, 0, stream>>>(nw2, nw2p, 512, 512, 0);
  pack_w<<<128, 256, 0, stream>>>(nw3, nw3p, 512, 512, 0);
  fold_w3<<<513, 64, 0, stream>>>(ew3, few, eb3, feb, w3f);
  cast_node<<<7168, 256, 0, stream>>>(states, nodeb, (int)(NV * 512 / 8));

  // Pass 1
  gemm64_0<<<dim3(448, 2), 256, 0, stream>>>(nodeb, w1p, PQ);
  edge0_kernel<<<4096, 512, 0, stream>>>(PQ, w2p, w3p, eb1, eb2, eg, ebt, eb3, aggb);
  // Node update + head + PQ for pass 2 (fused)
  node_mega<<<448, 512, 0, stream>>>(nodeb, aggb, nw1p, nw2p, nw3p, w1p,
                                     nb1, nb2, ng, nbt, nb3, fnw, fnb, PQ, out);
  // Pass 2 edge head
  edge1_kernel<<<4096, 512, 0, stream>>>(PQ, w2p, eb1, eb2, eg, ebt, w3f, out);
}

// Round 15
// 580.261 us; speedup vs baseline: 1.2509x; 1.0214x over previous
//
#include <hip/hip_runtime.h>

#define LN_EPS 1e-5f

typedef unsigned short u16;
typedef u16 u16x8 __attribute__((ext_vector_type(8)));
typedef __bf16 bf16x8 __attribute__((ext_vector_type(8)));
typedef float f32x4 __attribute__((ext_vector_type(4)));
typedef float f32x2 __attribute__((ext_vector_type(2)));

__device__ __forceinline__ u16 f2bf(float f){
  return __builtin_bit_cast(u16, (__bf16)f);
}
__device__ __forceinline__ float bf2f(u16 b){
  return (float)__builtin_bit_cast(__bf16, b);
}
__device__ __forceinline__ f32x4 mfma16(u16x8 a, u16x8 b, f32x4 c){
  return __builtin_amdgcn_mfma_f32_16x16x32_bf16(
      __builtin_bit_cast(bf16x8, a), __builtin_bit_cast(bf16x8, b), c, 0, 0, 0);
}
// LDS h-tile: [64 rows][512 k] bf16, XOR swizzle on k (8-elem granules)
__device__ __forceinline__ int uidx(int row, int k){
  return row * 512 + (k ^ ((row & 7) << 3));
}

__device__ __forceinline__ void zero_acc(f32x4 (&acc)[4][4]){
  #pragma unroll
  for (int mt = 0; mt < 4; ++mt)
    #pragma unroll
    for (int ct = 0; ct < 4; ++ct){
      f32x4 z = {0.f, 0.f, 0.f, 0.f};
      acc[mt][ct] = z;
    }
}

// Issue first kt's 4 B-fragment loads BEFORE the preceding barrier (in flight
// across s_barrier; hides cold-start L2 latency).
__device__ __forceinline__ void preload_b4(const u16* __restrict__ Bp, int wave, int lane,
                                           u16x8 (&b)[4]){
  const u16* bb = Bp + ((size_t)(wave * 4) * 64 + lane) * 8;
  #pragma unroll
  for (int ct = 0; ct < 4; ++ct) b[ct] = *(const u16x8*)&bb[ct * 512];
}

// GEMM, A from LDS (64 rows), B from global (N=512 packing, kt-stride 16384),
// 1-deep register prefetch. b_cur arrives preloaded.
__device__ __forceinline__ void gemm_pipe(const u16* hA, const u16* __restrict__ Bp,
                                          f32x4 (&acc)[4][4], int wave, int lane,
                                          u16x8 (&b_cur)[4]){
  int lrow = lane & 15, lhi = lane >> 4;
  const u16* bb = Bp + ((size_t)(wave * 4) * 64 + lane) * 8;
  u16x8 b_nxt[4], a[4];
  #pragma unroll
  for (int kt = 0; kt < 16; ++kt){
    #pragma unroll
    for (int mt = 0; mt < 4; ++mt)
      a[mt] = *(const u16x8*)&hA[uidx(mt * 16 + lrow, kt * 32 + lhi * 8)];
    if (kt < 15){
      #pragma unroll
      for (int ct = 0; ct < 4; ++ct)
        b_nxt[ct] = *(const u16x8*)&bb[(size_t)(kt + 1) * 16384 + ct * 512];
    }
    __builtin_amdgcn_s_setprio(1);
    #pragma unroll
    for (int ct = 0; ct < 4; ++ct)
      #pragma unroll
      for (int mt = 0; mt < 4; ++mt)
        acc[mt][ct] = mfma16(a[mt], b_cur[ct], acc[mt][ct]);
    __builtin_amdgcn_s_setprio(0);
    #pragma unroll
    for (int ct = 0; ct < 4; ++ct) b_cur[ct] = b_nxt[ct];
  }
}

// K=1024 GEMM, A rows from TWO global sources (nodeb | hsumb), B packed K=1024
// (kt-stride 16384, KT=32).
__device__ __forceinline__ void gemm_k1024_gA(const u16* __restrict__ A0,
                                              const u16* __restrict__ A1, size_t row0,
                                              const u16* __restrict__ Bp,
                                              f32x4 (&acc)[4][4], int wave, int lane){
  int lrow = lane & 15, lhi = lane >> 4;
  const u16* bb = Bp + ((size_t)(wave * 4) * 64 + lane) * 8;
  const u16* a0 = A0 + (row0 + lrow) * 512 + lhi * 8;
  const u16* a1 = A1 + (row0 + lrow) * 512 + lhi * 8;
  u16x8 b_cur[4], b_nxt[4], a[4];
  #pragma unroll
  for (int ct = 0; ct < 4; ++ct) b_cur[ct] = *(const u16x8*)&bb[ct * 512];
  #pragma unroll
  for (int kt = 0; kt < 32; ++kt){
    const u16* ab = (kt < 16) ? a0 : a1;
    int kk = (kt & 15) * 32;
    #pragma unroll
    for (int mt = 0; mt < 4; ++mt)
      a[mt] = *(const u16x8*)&ab[mt * 8192 + kk];
    if (kt < 31){
      #pragma unroll
      for (int ct = 0; ct < 4; ++ct)
        b_nxt[ct] = *(const u16x8*)&bb[(size_t)(kt + 1) * 16384 + ct * 512];
    }
    __builtin_amdgcn_s_setprio(1);
    #pragma unroll
    for (int ct = 0; ct < 4; ++ct)
      #pragma unroll
      for (int mt = 0; mt < 4; ++mt)
        acc[mt][ct] = mfma16(a[mt], b_cur[ct], acc[mt][ct]);
    __builtin_amdgcn_s_setprio(0);
    #pragma unroll
    for (int ct = 0; ct < 4; ++ct) b_cur[ct] = b_nxt[ct];
  }
}

// GEMM over hA with custom B base/kt-stride (for N=1024 w1p packing).
__device__ __forceinline__ void gemm_pipe_s(const u16* hA, const u16* __restrict__ bbBase,
                                            int ktStride, f32x4 (&acc)[4][4],
                                            int lane){
  int lrow = lane & 15, lhi = lane >> 4;
  u16x8 b_cur[4], b_nxt[4], a[4];
  #pragma unroll
  for (int ct = 0; ct < 4; ++ct) b_cur[ct] = *(const u16x8*)&bbBase[ct * 512];
  #pragma unroll
  for (int kt = 0; kt < 16; ++kt){
    #pragma unroll
    for (int mt = 0; mt < 4; ++mt)
      a[mt] = *(const u16x8*)&hA[uidx(mt * 16 + lrow, kt * 32 + lhi * 8)];
    if (kt < 15){
      #pragma unroll
      for (int ct = 0; ct < 4; ++ct)
        b_nxt[ct] = *(const u16x8*)&bbBase[(size_t)(kt + 1) * ktStride + ct * 512];
    }
    __builtin_amdgcn_s_setprio(1);
    #pragma unroll
    for (int ct = 0; ct < 4; ++ct)
      #pragma unroll
      for (int mt = 0; mt < 4; ++mt)
        acc[mt][ct] = mfma16(a[mt], b_cur[ct], acc[mt][ct]);
    __builtin_amdgcn_s_setprio(0);
    #pragma unroll
    for (int ct = 0; ct < 4; ++ct) b_cur[ct] = b_nxt[ct];
  }
}

__device__ __forceinline__ void add_bias8(f32x4 (&acc)[4][4], const float* __restrict__ b,
                                          int wave, int lane){
  int lrow = lane & 15;
  #pragma unroll
  for (int ct = 0; ct < 4; ++ct){
    float bb = b[wave * 64 + ct * 16 + lrow];
    #pragma unroll
    for (int mt = 0; mt < 4; ++mt)
      #pragma unroll
      for (int r = 0; r < 4; ++r) acc[mt][ct][r] += bb;
  }
}

// acc += bias; relu; write bf16 into hA (swizzled). (r1 stage of node MLP.)
__device__ __forceinline__ void relu_to_lds(f32x4 (&acc)[4][4], u16* hA,
                                            const float* __restrict__ b,
                                            int wave, int lane){
  int lrow = lane & 15, lhi = lane >> 4;
  #pragma unroll
  for (int ct = 0; ct < 4; ++ct){
    int c = wave * 64 + ct * 16 + lrow;
    float bb = b[c];
    #pragma unroll
    for (int mt = 0; mt < 4; ++mt)
      #pragma unroll
      for (int r = 0; r < 4; ++r){
        int row = mt * 16 + lhi * 4 + r;
        hA[uidx(row, c)] = f2bf(fmaxf(acc[mt][ct][r] + bb, 0.f));
      }
  }
}

// acc += b2; LayerNorm over 512 cols per row; relu.
// TO_ACC=0: write bf16 into hA (swizzled); TO_ACC=1: result into acc.
template<int TO_ACC>
__device__ __forceinline__ void ln_relu8_t(f32x4 (&acc)[4][4], u16* hA,
    f32x2 (*stats)[8], f32x2* mufb,
    const float* __restrict__ b2, const float* __restrict__ g, const float* __restrict__ bt,
    int wave, int lane, int tid)
{
  int lrow = lane & 15, lhi = lane >> 4;
  float s1[4][4], s2[4][4];
  #pragma unroll
  for (int mt = 0; mt < 4; ++mt)
    #pragma unroll
    for (int r = 0; r < 4; ++r){ s1[mt][r] = 0.f; s2[mt][r] = 0.f; }
  #pragma unroll
  for (int ct = 0; ct < 4; ++ct){
    int c = wave * 64 + ct * 16 + lrow;
    float bb = b2[c];
    #pragma unroll
    for (int mt = 0; mt < 4; ++mt)
      #pragma unroll
      for (int r = 0; r < 4; ++r){
        float x = acc[mt][ct][r] + bb;
        acc[mt][ct][r] = x;
        s1[mt][r] += x; s2[mt][r] += x * x;
      }
  }
  #pragma unroll
  for (int off = 1; off < 16; off <<= 1){
    #pragma unroll
    for (int mt = 0; mt < 4; ++mt)
      #pragma unroll
      for (int r = 0; r < 4; ++r){
        s1[mt][r] += __shfl_xor(s1[mt][r], off);
        s2[mt][r] += __shfl_xor(s2[mt][r], off);
      }
  }
  float sa1 = 0.f, sa2 = 0.f;
  #pragma unroll
  for (int mt = 0; mt < 4; ++mt)
    #pragma unroll
    for (int r = 0; r < 4; ++r)
      if (lrow == mt * 4 + r){ sa1 = s1[mt][r]; sa2 = s2[mt][r]; }
  int rowa = (lrow >> 2) * 16 + lhi * 4 + (lrow & 3);
  f32x2 pa = {sa1, sa2};
  stats[rowa][wave] = pa;
  __syncthreads();              // also: all waves done reading hA (prev GEMM)
  if (tid < 64){
    float a = 0.f, b = 0.f;
    #pragma unroll
    for (int w = 0; w < 8; ++w){ a += stats[tid][w][0]; b += stats[tid][w][1]; }
    float mu  = a * (1.f / 512.f);
    float var = b * (1.f / 512.f) - mu * mu;
    f32x2 mr = {mu, rsqrtf(fmaxf(var, 0.f) + LN_EPS)};
    mufb[tid] = mr;
  }
  __syncthreads();
  float gv[4], btv[4];
  #pragma unroll
  for (int ct = 0; ct < 4; ++ct){
    int c = wave * 64 + ct * 16 + lrow;
    gv[ct] = g[c]; btv[ct] = bt[c];
  }
  #pragma unroll
  for (int mt = 0; mt < 4; ++mt)
    #pragma unroll
    for (int r = 0; r < 4; ++r){
      int row = mt * 16 + lhi * 4 + r;
      f32x2 mr = mufb[row];
      #pragma unroll
      for (int ct = 0; ct < 4; ++ct){
        int c = wave * 64 + ct * 16 + lrow;
        float x = (acc[mt][ct][r] - mr[0]) * mr[1] * gv[ct] + btv[ct];
        if (TO_ACC) acc[mt][ct][r] = fmaxf(x, 0.f);
        else        hA[uidx(row, c)] = f2bf(fmaxf(x, 0.f));
      }
    }
  // TO_ACC=0 caller: barrier before any cross-thread hA read.
}

// dot each row with weight vector w; per-wave partial -> stats[row][wave].x
__device__ __forceinline__ void head_partial8(f32x4 (&acc)[4][4], const float* __restrict__ w,
                                              f32x2 (*stats)[8], int wave, int lane)
{
  int lrow = lane & 15, lhi = lane >> 4;
  float hs[4][4];
  #pragma unroll
  for (int mt = 0; mt < 4; ++mt)
    #pragma unroll
    for (int r = 0; r < 4; ++r) hs[mt][r] = 0.f;
  #pragma unroll
  for (int ct = 0; ct < 4; ++ct){
    int c = wave * 64 + ct * 16 + lrow;
    float f = w[c];
    #pragma unroll
    for (int mt = 0; mt < 4; ++mt)
      #pragma unroll
      for (int r = 0; r < 4; ++r) hs[mt][r] += acc[mt][ct][r] * f;
  }
  #pragma unroll
  for (int off = 1; off < 16; off <<= 1)
    #pragma unroll
    for (int mt = 0; mt < 4; ++mt)
      #pragma unroll
      for (int r = 0; r < 4; ++r) hs[mt][r] += __shfl_xor(hs[mt][r], off);
  float sa = 0.f;
  #pragma unroll
  for (int mt = 0; mt < 4; ++mt)
    #pragma unroll
    for (int r = 0; r < 4; ++r)
      if (lrow == mt * 4 + r) sa = hs[mt][r];
  int rowa = (lrow >> 2) * 16 + lhi * 4 + (lrow & 3);
  f32x2 pa = {sa, 0.f};
  stats[rowa][wave] = pa;
}

// Staging: h1 = relu(P[i]+Q[j]+b1) into hA rows 0..48 (+ zero pad rows 49..63).
__device__ __forceinline__ void stage_h1(const u16* __restrict__ PQ, int gg, u16* hA,
                                         const float* bias, int wave, int lane){
  const u16* Pg = PQ + (size_t)gg * 7 * 1024;
  u16x8 pA, qA, pB, qB;
  {
    int e = wave;
    int i = e / 7, j = e % 7;
    pA = *(const u16x8*)&Pg[(size_t)i * 1024 + lane * 8];
    qA = *(const u16x8*)&Pg[(size_t)j * 1024 + 512 + lane * 8];
  }
  #pragma unroll
  for (int it = 0; it < 8; ++it){
    int e = it * 8 + wave;
    if (it < 7){
      int e2 = e + 8;
      if (e2 < 49){
        int i = e2 / 7, j = e2 % 7;
        pB = *(const u16x8*)&Pg[(size_t)i * 1024 + lane * 8];
        qB = *(const u16x8*)&Pg[(size_t)j * 1024 + 512 + lane * 8];
      }
    }
    u16x8 o;
    if (e < 49){
      #pragma unroll
      for (int u = 0; u < 8; ++u)
        o[u] = f2bf(fmaxf(bf2f(pA[u]) + bf2f(qA[u]) + bias[u], 0.f));
    } else {
      #pragma unroll
      for (int u = 0; u < 8; ++u) o[u] = 0;
    }
    *(u16x8*)&hA[uidx(e, lane * 8)] = o;
    pA = pB; qA = qB;
  }
}

// ======== edge pass 0: stage -> GEMM1(w2) -> LN -> colsum -> hsum (global) ======
// w3 GEMM folded into node pass: agg@nw1b = hsum@(w3@nw1b) + 7*(b3@nw1b).
__global__ __launch_bounds__(512, 2) void edge0_kernel(
    const u16* __restrict__ PQ, const u16* __restrict__ w2p,
    const float* __restrict__ b1, const float* __restrict__ b2,
    const float* __restrict__ g, const float* __restrict__ bt,
    u16* __restrict__ hsum)
{
  __shared__ alignas(16) u16 hA[64 * 512];
  __shared__ f32x2 stats[64][8];
  __shared__ f32x2 mufb[64];
  int gidx = blockIdx.x;
  int tid = threadIdx.x;
  int wave = tid >> 6, lane = tid & 63;

  const float4* b1v = (const float4*)b1;
  float4 ba = b1v[lane * 2], bb2 = b1v[lane * 2 + 1];
  float bias[8] = {ba.x, ba.y, ba.z, ba.w, bb2.x, bb2.y, bb2.z, bb2.w};

  stage_h1(PQ, gidx, hA, bias, wave, lane);
  u16x8 bpre[4];
  preload_b4(w2p, wave, lane, bpre);
  __syncthreads();

  f32x4 acc[4][4];
  zero_acc(acc);
  gemm_pipe(hA, w2p, acc, wave, lane, bpre);
  ln_relu8_t<0>(acc, hA, stats, mufb, b2, g, bt, wave, lane, tid);
  __syncthreads();                    // h2n rows 0..48 visible
  // column sums: hsum[i][c] = sum_j h2n[7i+j][c] -> global (bf16, coalesced)
  {
    int c = tid;   // 0..511
    #pragma unroll
    for (int i = 0; i < 7; ++i){
      float s = 0.f;
      #pragma unroll
      for (int j = 0; j < 7; ++j)
        s += bf2f(hA[uidx(7 * i + j, c)]);
      hsum[((size_t)(gidx * 7 + i)) * 512 + c] = f2bf(s);
    }
  }
}

// ============ edge pass 1: w3 folded to a vector (w3f = ew3@few) ============
__global__ __launch_bounds__(512, 2) void edge1_kernel(
    const u16* __restrict__ PQ, const u16* __restrict__ w2p,
    const float* __restrict__ b1, const float* __restrict__ b2,
    const float* __restrict__ g, const float* __restrict__ bt,
    const float* __restrict__ w3f, float* __restrict__ out)
{
  __shared__ alignas(16) u16 hA[64 * 512];
  __shared__ f32x2 stats[64][8];
  __shared__ f32x2 mufb[64];
  int gidx = blockIdx.x;
  int tid = threadIdx.x;
  int wave = tid >> 6, lane = tid & 63;

  const float4* b1v = (const float4*)b1;
  float4 ba = b1v[lane * 2], bb2 = b1v[lane * 2 + 1];
  float bias[8] = {ba.x, ba.y, ba.z, ba.w, bb2.x, bb2.y, bb2.z, bb2.w};

  stage_h1(PQ, gidx, hA, bias, wave, lane);
  u16x8 bpre[4];
  preload_b4(w2p, wave, lane, bpre);
  __syncthreads();

  f32x4 acc[4][4];
  zero_acc(acc);
  gemm_pipe(hA, w2p, acc, wave, lane, bpre);
  ln_relu8_t<1>(acc, hA, stats, mufb, b2, g, bt, wave, lane, tid);  // acc := relu(LN)
  head_partial8(acc, w3f, stats, wave, lane);
  __syncthreads();
  if (tid < 49){
    float s = w3f[512];   // eb3.few + feb
    #pragma unroll
    for (int w = 0; w < 8; ++w) s += stats[tid][w][0];
    out[(size_t)gidx * 56 + 7 + tid] = s;
  }
}

// ==== node mega-kernel: r1 -> h2 -> LN -> node2 (+head) -> PQ (pass 2) ====
// r1 = relu(node@nw1a + hsum@w3n + bvec), B = nw1cat = [nw1a | w3n] packed.
__global__ __launch_bounds__(512, 2) void node_mega(
    const u16* __restrict__ nodeb, const u16* __restrict__ hsumb,
    const u16* __restrict__ nw1cat, const u16* __restrict__ nw2p,
    const u16* __restrict__ nw3p, const u16* __restrict__ w1p,
    const float* __restrict__ bvec, const float* __restrict__ nb2,
    const float* __restrict__ ng, const float* __restrict__ nbt,
    const float* __restrict__ nb3, const float* __restrict__ hw,
    const float* __restrict__ hb,
    u16* __restrict__ PQ, float* __restrict__ out)
{
  __shared__ alignas(16) u16 hA[64 * 512];
  __shared__ f32x2 stats[64][8];
  __shared__ f32x2 mufb[64];
  int tid = threadIdx.x;
  int wave = tid >> 6, lane = tid & 63;
  int lrow = lane & 15, lhi = lane >> 4;
  size_t row0 = (size_t)blockIdx.x * 64;

  // r1 = relu([nodeb|hsumb] @ [nw1a|w3n] + bvec)  (K=1024, A from global)
  f32x4 acc[4][4];
  zero_acc(acc);
  gemm_k1024_gA(nodeb, hsumb, row0, nw1cat, acc, wave, lane);
  relu_to_lds(acc, hA, bvec, wave, lane);
  u16x8 bpre[4];
  preload_b4(nw2p, wave, lane, bpre);
  __syncthreads();
  // h2 = r1 @ nw2 (+nb2 in LN) -> LN -> relu -> hA
  zero_acc(acc);
  gemm_pipe(hA, nw2p, acc, wave, lane, bpre);
  ln_relu8_t<0>(acc, hA, stats, mufb, nb2, ng, nbt, wave, lane, tid);
  preload_b4(nw3p, wave, lane, bpre);
  __syncthreads();
  // node2 = h2n @ nw3 + nb3
  zero_acc(acc);
  gemm_pipe(hA, nw3p, acc, wave, lane, bpre);
  add_bias8(acc, nb3, wave, lane);
  __syncthreads();   // all GEMM reads of hA (h2n) done before overwrite
  // node2 -> hA (for PQ GEMMs); head partial
  #pragma unroll
  for (int ct = 0; ct < 4; ++ct){
    int c = wave * 64 + ct * 16 + lrow;
    #pragma unroll
    for (int mt = 0; mt < 4; ++mt)
      #pragma unroll
      for (int r = 0; r < 4; ++r)
        hA[uidx(mt * 16 + lhi * 4 + r, c)] = f2bf(acc[mt][ct][r]);
  }
  head_partial8(acc, hw, stats, wave, lane);
  __syncthreads();   // node2 + stats visible
  if (tid < 64){
    size_t v = row0 + tid;
    float s = hb[0];
    #pragma unroll
    for (int w = 0; w < 8; ++w) s += stats[tid][w][0];
    out[(v / 7) * 56 + (v % 7)] = s;
  }
  // PQ = node2 @ w1p  (N=1024, two 512-col passes; w1p nt=64 -> kt-stride 32768)
  #pragma unroll
  for (int p = 0; p < 2; ++p){
    zero_acc(acc);
    const u16* bbBase = w1p + (((size_t)(p * 32) + wave * 4) * 64 + lane) * 8;
    gemm_pipe_s(hA, bbBase, 32768, acc, lane);
    #pragma unroll
    for (int ct = 0; ct < 4; ++ct){
      int c = p * 512 + wave * 64 + ct * 16 + lrow;
      #pragma unroll
      for (int mt = 0; mt < 4; ++mt)
        #pragma unroll
        for (int r = 0; r < 4; ++r){
          size_t grow = row0 + mt * 16 + lhi * 4 + r;
          PQ[grow * 1024 + c] = f2bf(acc[mt][ct][r]);
        }
    }
  }
}

// gemm64 MODE0 (r5 form): PQ = nodeb @ w1p (pass 1), N=1024 via blockIdx.y slabs.
__global__ __launch_bounds__(256, 2) void gemm64_0(
    const u16* __restrict__ A0, const u16* __restrict__ Bp, u16* __restrict__ Cout)
{
  int tid = threadIdx.x;
  int wave = tid >> 6, lane = tid & 63;
  int lrow = lane & 15, lhi = lane >> 4;
  size_t row0 = (size_t)blockIdx.x * 64;
  int coff = blockIdx.y * 512;
  const u16* bb = Bp + (((size_t)(coff >> 4) + wave * 8) * 64 + lane) * 8;
  f32x4 acc[4][8];
  #pragma unroll
  for (int mt = 0; mt < 4; ++mt)
    #pragma unroll
    for (int ct = 0; ct < 8; ++ct){
      f32x4 z = {0.f, 0.f, 0.f, 0.f};
      acc[mt][ct] = z;
    }
  u16x8 b_cur[8], b_nxt[8];
  #pragma unroll
  for (int ct = 0; ct < 8; ++ct) b_cur[ct] = *(const u16x8*)&bb[ct * 512];
  #pragma unroll
  for (int kt = 0; kt < 16; ++kt){
    u16x8 af[4];
    #pragma unroll
    for (int mt = 0; mt < 4; ++mt)
      af[mt] = *(const u16x8*)&A0[(row0 + mt * 16 + lrow) * 512 + kt * 32 + lhi * 8];
    if (kt < 15){
      #pragma unroll
      for (int ct = 0; ct < 8; ++ct)
        b_nxt[ct] = *(const u16x8*)&bb[((size_t)(kt + 1) * 64 * 64 + ct * 64) * 8];
    }
    __builtin_amdgcn_s_setprio(1);
    #pragma unroll
    for (int ct = 0; ct < 8; ++ct)
      #pragma unroll
      for (int mt = 0; mt < 4; ++mt) acc[mt][ct] = mfma16(af[mt], b_cur[ct], acc[mt][ct]);
    __builtin_amdgcn_s_setprio(0);
    #pragma unroll
    for (int ct = 0; ct < 8; ++ct) b_cur[ct] = b_nxt[ct];
  }
  #pragma unroll
  for (int ct = 0; ct < 8; ++ct){
    int c = coff + wave * 128 + ct * 16 + lrow;
    #pragma unroll
    for (int mt = 0; mt < 4; ++mt)
      #pragma unroll
      for (int r = 0; r < 4; ++r){
        size_t grow = row0 + mt * 16 + lhi * 4 + r;
        Cout[grow * 1024 + c] = f2bf(acc[mt][ct][r]);
      }
  }
}

// w3n = ew3(f32) @ nw1b(packed bf16): 512x512 out, K=512. 8 blocks x 256 thr.
// A fragments cast from f32 on the fly; C written f32 row-major (packed later).
__global__ __launch_bounds__(256) void gemm_w3n(
    const float* __restrict__ A, const u16* __restrict__ Bp, float* __restrict__ C)
{
  int tid = threadIdx.x;
  int wave = tid >> 6, lane = tid & 63;
  int lrow = lane & 15, lhi = lane >> 4;
  size_t row0 = (size_t)blockIdx.x * 64;
  const u16* bb = Bp + (((size_t)(wave * 8)) * 64 + lane) * 8;
  f32x4 acc[4][8];
  #pragma unroll
  for (int mt = 0; mt < 4; ++mt)
    #pragma unroll
    for (int ct = 0; ct < 8; ++ct){
      f32x4 z = {0.f, 0.f, 0.f, 0.f};
      acc[mt][ct] = z;
    }
  for (int kt = 0; kt < 16; ++kt){
    u16x8 af[4], bv[8];
    #pragma unroll
    for (int mt = 0; mt < 4; ++mt){
      const float* ar = A + (row0 + mt * 16 + lrow) * 512 + kt * 32 + lhi * 8;
      float4 v0 = *(const float4*)ar, v1 = *(const float4*)(ar + 4);
      af[mt][0] = f2bf(v0.x); af[mt][1] = f2bf(v0.y);
      af[mt][2] = f2bf(v0.z); af[mt][3] = f2bf(v0.w);
      af[mt][4] = f2bf(v1.x); af[mt][5] = f2bf(v1.y);
      af[mt][6] = f2bf(v1.z); af[mt][7] = f2bf(v1.w);
    }
    #pragma unroll
    for (int ct = 0; ct < 8; ++ct)
      bv[ct] = *(const u16x8*)&bb[(size_t)kt * 16384 + ct * 512];
    #pragma unroll
    for (int ct = 0; ct < 8; ++ct)
      #pragma unroll
      for (int mt = 0; mt < 4; ++mt) acc[mt][ct] = mfma16(af[mt], bv[ct], acc[mt][ct]);
  }
  #pragma unroll
  for (int ct = 0; ct < 8; ++ct){
    int c = wave * 128 + ct * 16 + lrow;
    #pragma unroll
    for (int mt = 0; mt < 4; ++mt)
      #pragma unroll
      for (int r = 0; r < 4; ++r){
        size_t grow = row0 + mt * 16 + lhi * 4 + r;
        C[grow * 512 + c] = acc[mt][ct][r];
      }
  }
}

// bvec[c] = nb1[c] + 7 * sum_m b3[m] * nw1[512+m][c]   (1 block, 512 threads)
__global__ void fold_bvec(const float* __restrict__ nb1, const float* __restrict__ b3,
                          const float* __restrict__ nw1, float* __restrict__ bvec)
{
  int c = threadIdx.x;
  float s = 0.f;
  for (int m = 0; m < 512; ++m)
    s += b3[m] * nw1[(size_t)(512 + m) * 512 + c];
  bvec[c] = nb1[c] + 7.f * s;
}

// w3f[k] = sum_c ew3[k][c]*few[c]  (f32); w3f[512] = eb3.few + feb
__global__ void fold_w3(const float* __restrict__ W3, const float* __restrict__ hw,
                        const float* __restrict__ b3, const float* __restrict__ hb,
                        float* __restrict__ w3f)
{
  int k = blockIdx.x, l = threadIdx.x;
  const float* row = (k < 512) ? (W3 + (size_t)k * 512) : b3;
  float s = 0.f;
  for (int c = l; c < 512; c += 64) s += row[c] * hw[c];
  #pragma unroll
  for (int off = 32; off; off >>= 1) s += __shfl_down(s, off);
  if (l == 0) w3f[k] = (k < 512) ? s : s + hb[0];
}

// Pack f32 weight [K][N] into MFMA B-fragment order (bf16).
__global__ void pack_w(const float* __restrict__ W, u16* __restrict__ dst,
                       int K, int N, int w1mode)
{
  int idx = blockIdx.x * 256 + threadIdx.x;
  int total = (K >> 5) * (N >> 4) * 64;
  if (idx >= total) return;
  int lane = idx & 63;
  int t = idx >> 6;
  int nt = N >> 4;
  int ct = t % nt;
  int kt = t / nt;
  int c  = ct * 16 + (lane & 15);
  int k0 = kt * 32 + (lane >> 4) * 8;
  u16x8 o;
  #pragma unroll
  for (int j = 0; j < 8; ++j){
    int k = k0 + j;
    float v;
    if (w1mode){
      v = (c < 512) ? W[(size_t)k * 512 + c] : W[(size_t)(k + 512) * 512 + (c - 512)];
    } else {
      v = W[(size_t)k * N + c];
    }
    o[j] = f2bf(v);
  }
  *(u16x8*)&dst[(size_t)idx * 8] = o;
}

__global__ void cast_node(const float* __restrict__ src, u16* __restrict__ dst, int n8){
  int idx = blockIdx.x * 256 + threadIdx.x;
  if (idx >= n8) return;
  const float4* s = (const float4*)src;
  float4 a = s[(size_t)idx * 2], b = s[(size_t)idx * 2 + 1];
  u16x8 o;
  o[0] = f2bf(a.x); o[1] = f2bf(a.y); o[2] = f2bf(a.z); o[3] = f2bf(a.w);
  o[4] = f2bf(b.x); o[5] = f2bf(b.y); o[6] = f2bf(b.z); o[7] = f2bf(b.w);
  *(u16x8*)&dst[(size_t)idx * 8] = o;
}

extern "C" void kernel_launch(void* const* d_in, const int* in_sizes, int n_in,
                              void* d_out, int out_size, void* d_ws, size_t ws_size,
                              hipStream_t stream)
{
  (void)in_sizes; (void)n_in; (void)out_size; (void)ws_size;
  const float* states = (const float*)d_in[0];
  const float* ew1 = (const float*)d_in[1];
  const float* eb1 = (const float*)d_in[2];
  const float* ew2 = (const float*)d_in[3];
  const float* eb2 = (const float*)d_in[4];
  const float* eg  = (const float*)d_in[5];
  const float* ebt = (const float*)d_in[6];
  const float* ew3 = (const float*)d_in[7];
  const float* eb3 = (const float*)d_in[8];
  const float* nw1 = (const float*)d_in[9];
  const float* nb1 = (const float*)d_in[10];
  const float* nw2 = (const float*)d_in[11];
  const float* nb2 = (const float*)d_in[12];
  const float* ng  = (const float*)d_in[13];
  const float* nbt = (const float*)d_in[14];
  const float* nw3 = (const float*)d_in[15];
  const float* nb3 = (const float*)d_in[16];
  const float* fnw = (const float*)d_in[17];
  const float* fnb = (const float*)d_in[18];
  const float* few = (const float*)d_in[19];
  const float* feb = (const float*)d_in[20];
  float* out = (float*)d_out;

  char* ws = (char*)d_ws;
  size_t off = 0;
  auto alloc = [&](size_t bytes) -> void* {
    void* p = ws + off;
    off += (bytes + 255) & ~(size_t)255;
    return p;
  };
  const size_t NV = 28672;  // B*n
  u16* PQ     = (u16*)alloc(NV * 1024 * 2);   // [NV][P(512)|Q(512)] bf16
  u16* nodeb  = (u16*)alloc(NV * 512 * 2);
  u16* hsumb  = (u16*)alloc(NV * 512 * 2);
  u16* w1p    = (u16*)alloc(512 * 1024 * 2);
  u16* nw1cat = (u16*)alloc(1024 * 512 * 2);  // [nw1a packed | w3n packed]
  u16* nw1bp  = (u16*)alloc(512 * 512 * 2);
  u16* w2p    = (u16*)alloc(512 * 512 * 2);
  u16* nw2p   = (u16*)alloc(512 * 512 * 2);
  u16* nw3p   = (u16*)alloc(512 * 512 * 2);
  float* w3n  = (float*)alloc(512 * 512 * 4);
  float* w3f  = (float*)alloc(513 * 4);
  float* bvec = (float*)alloc(512 * 4);

  pack_w<<<256, 256, 0, stream>>>(ew1, w1p, 512, 1024, 1);
  pack_w<<<128, 256, 0, stream>>>(nw1, nw1cat, 512, 512, 0);             // nw1a
  pack_w<<<128, 256, 0, stream>>>(nw1 + 512 * 512, nw1bp, 512, 512, 0);  // nw1b
  pack_w<<<128, 256, 0, stream>>>(ew2, w2p, 512, 512, 0);
  pack_w<<<128, 256, 0, stream>>>(nw2, nw2p, 512, 512, 0);
  pack_w<<<128, 256, 0, stream>>>(nw3, nw3p, 512, 512, 0);
  fold_w3<<<513, 64, 0, stream>>>(ew3, few, eb3, feb, w3f);
  fold_bvec<<<1, 512, 0, stream>>>(nb1, eb3, nw1, bvec);
  gemm_w3n<<<8, 256, 0, stream>>>(ew3, nw1bp, w3n);
  pack_w<<<128, 256, 0, stream>>>(w3n, nw1cat + 512 * 512, 512, 512, 0); // w3n
  cast_node<<<7168, 256, 0, stream>>>(states, nodeb, (int)(NV * 512 / 8));

  // Pass 1
  gemm64_0<<<dim3(448, 2), 256, 0, stream>>>(nodeb, w1p, PQ);
  edge0_kernel<<<4096, 512, 0, stream>>>(PQ, w2p, eb1, eb2, eg, ebt, hsumb);
  // Node update + head + PQ for pass 2 (fused)
  node_mega<<<448, 512, 0, stream>>>(nodeb, hsumb, nw1cat, nw2p, nw3p, w1p,
                                     bvec, nb2, ng, nbt, nb3, fnw, fnb, PQ, out);
  // Pass 2 edge head
  edge1_kernel<<<4096, 512, 0, stream>>>(PQ, w2p, eb1, eb2, eg, ebt, w3f, out);
}